// Round 4
// baseline (316.566 us; speedup 1.0000x reference)
//
#include <hip/hip_runtime.h>
#include <math.h>

#define Hh 128
#define Ww 128
#define HW (128*128)
#define PITCH 130
#define PADPX (130*130)

typedef unsigned short u16;
typedef unsigned int uint;
typedef __attribute__((ext_vector_type(8))) short short8;
typedef __attribute__((ext_vector_type(4))) float f32x4;

__device__ inline u16 bf16_rne(float v) {
  uint x = __float_as_uint(v);
  uint r = (x + 0x7fffu + ((x >> 16) & 1u)) >> 16;
  return (u16)r;
}
__device__ inline float bf16f(u16 u) { return __uint_as_float(((uint)u) << 16); }

// ---------------- zero the halo edges of a padded NHWC buffer ----------------
__global__ __launch_bounds__(256) void zero_edge_k(u16* __restrict__ buf, int C2) {
  int per_px = C2 >> 3;             // uint4 chunks per pixel
  int total = 516 * per_px;         // 516 edge pixels
  int idx = blockIdx.x * 256 + threadIdx.x;
  int b = blockIdx.y;
  if (idx >= total) return;
  int e = idx / per_px, q = idx - e * per_px;
  int y, x;
  if (e < 130)      { y = 0;   x = e; }
  else if (e < 260) { y = 129; x = e - 130; }
  else { int j = e - 260; y = 1 + (j >> 1); x = (j & 1) ? 129 : 0; }
  *(uint4*)&buf[((size_t)b * PADPX + (size_t)(y * PITCH + x)) * C2 + q * 8] =
      make_uint4(0, 0, 0, 0);
}

// ---------------- prep: cond [B][133][HW] -> padded [B][PADPX][2][160] ----------------
__global__ __launch_bounds__(256) void prep_cond_k(const float* __restrict__ cond,
                                                   u16* __restrict__ out) {
  int p = blockIdx.x * 256 + threadIdx.x;
  int b = blockIdx.y;
  int y = p >> 7, x = p & 127;
  const float* cb = cond + (size_t)b * 133 * HW + p;
  u16* ob = out + ((size_t)b * PADPX + (size_t)((y + 1) * PITCH + x + 1)) * 320;
  for (int c = 0; c < 160; c += 4) {
    u16 hbuf[4], lbuf[4];
    #pragma unroll
    for (int j = 0; j < 4; j++) {
      float v = (c + j < 133) ? cb[(size_t)(c + j) * HW] : 0.f;
      u16 hi = bf16_rne(v);
      hbuf[j] = hi;
      lbuf[j] = bf16_rne(v - bf16f(hi));
    }
    *(uint2*)&ob[c] = *(uint2*)hbuf;
    *(uint2*)&ob[160 + c] = *(uint2*)lbuf;
  }
}

// ---------------- conv weight -> MFMA A-fragment layout ----------------
// frag id = ((t*NC + c)*2 + P)*NCOF + f ; 64 lanes x 8 bf16 (1KB)
__global__ __launch_bounds__(256) void wtrans_mfma_k(const float* __restrict__ w,
                                                     u16* __restrict__ wt,
                                                     int CIN, int NC, int NCOF) {
  int idx = blockIdx.x * 256 + threadIdx.x;
  int total = 9 * NC * 2 * NCOF * 64;
  if (idx >= total) return;
  int lane = idx & 63;
  int frag = idx >> 6;
  int f = frag % NCOF;
  int rest = frag / NCOF;
  int P = rest & 1; rest >>= 1;
  int c = rest % NC;
  int t = rest / NC;
  int co = f * 16 + (lane & 15);
  int ci0 = c * 32 + (lane >> 4) * 8;
  u16 buf[8];
  #pragma unroll
  for (int j = 0; j < 8; j++) {
    int ci = ci0 + j;
    float v = (ci < CIN) ? w[((size_t)co * CIN + ci) * 9 + t] : 0.f;
    u16 hi = bf16_rne(v);
    buf[j] = P ? bf16_rne(v - bf16f(hi)) : hi;
  }
  *(uint4*)&wt[(size_t)idx * 8] = *(uint4*)buf;
}

// ---------------- dcn weight -> A-frags over K=576 (ci = k*64 + dg*4 + c) ----------------
__global__ __launch_bounds__(256) void wtrans_dcn_mfma_k(const float* __restrict__ w,
                                                         u16* __restrict__ wt) {
  int idx = blockIdx.x * 256 + threadIdx.x;
  if (idx >= 18 * 2 * 4 * 64) return;
  int lane = idx & 63;
  int frag = idx >> 6;
  int f = frag & 3;
  int P = (frag >> 2) & 1;
  int chunk = frag >> 3;
  int co = f * 16 + (lane & 15);
  int ci0 = chunk * 32 + (lane >> 4) * 8;
  u16 buf[8];
  #pragma unroll
  for (int j = 0; j < 8; j++) {
    int ci = ci0 + j;
    int k = ci >> 6, cig = ci & 63;
    float v = w[((size_t)co * 64 + cig) * 9 + k];
    u16 hi = bf16_rne(v);
    buf[j] = P ? bf16_rne(v - bf16f(hi)) : hi;
  }
  *(uint4*)&wt[(size_t)idx * 8] = *(uint4*)buf;
}

// x [B][64][H][W] -> xt [B][16][H][W][4]
__global__ __launch_bounds__(256) void xtrans_k(const float* __restrict__ x,
                                                float* __restrict__ xt, int B) {
  int idx = blockIdx.x * 256 + threadIdx.x;
  int total = B * 16 * HW;
  if (idx >= total) return;
  int b = idx / (16 * HW);
  int r = idx % (16 * HW);
  int dg = r / HW, p = r % HW;
  const float* xb = x + ((size_t)b * 64 + dg * 4) * HW + p;
  float4 v;
  v.x = xb[0]; v.y = xb[HW]; v.z = xb[2 * HW]; v.w = xb[3 * HW];
  ((float4*)xt)[idx] = v;
}

// ---------------- conv3x3: direct-from-global MFMA, 3-term bf16 split ----------------
// in padded NHWC [b][PADPX][2][CINP]. Block = 128 thr (2 waves), tile 16x8 px.
// Wave covers 4 row-groups (pl) x 16 px. cog selects NCF cout-frags of NCOF.
template<int CINP, int NC, int NCF, int NCOF, int EPI>
__global__ __launch_bounds__(128) void conv_direct_k(
    const u16* __restrict__ in_hl, const u16* __restrict__ wt,
    const float* __restrict__ bias, u16* __restrict__ out_hl,
    float* __restrict__ offb, float* __restrict__ mskb,
    const float* __restrict__ flow, int cogroups)
{
  constexpr int C2 = 2 * CINP;
  const int tid = threadIdx.x;
  const int lane = tid & 63, wave = tid >> 6;
  const int b = blockIdx.z / cogroups, cog = blockIdx.z % cogroups;
  const int gx0 = blockIdx.x * 16;
  const int gy0 = blockIdx.y * 8 + wave * 4;

  f32x4 acc[4][NCF];
  #pragma unroll
  for (int i = 0; i < 4; i++)
    #pragma unroll
    for (int j = 0; j < NCF; j++) acc[i][j] = (f32x4)0.f;

  const u16* inb = in_hl + (size_t)b * PADPX * C2;
  const int xc = gx0 + (lane & 15);
  const int qoff = (lane >> 4) * 8;

  for (int c = 0; c < NC; c++) {
    const int ho = c * 32 + qoff;
    #pragma unroll
    for (int tap = 0; tap < 9; tap++) {
      const int dy = tap / 3 - 1, dx = tap % 3 - 1;
      short8 bh[4], bl[4];
      #pragma unroll
      for (int pl = 0; pl < 4; pl++) {
        size_t po = (size_t)((gy0 + pl + dy + 1) * PITCH + xc + dx + 1) * C2;
        bh[pl] = *(const short8*)&inb[po + ho];
        bl[pl] = *(const short8*)&inb[po + CINP + ho];
      }
      const u16* fH = wt + (((size_t)(tap * NC + c) * 2 + 0) * NCOF + cog * NCF) * 512
                      + (size_t)lane * 8;
      const u16* fL = fH + (size_t)NCOF * 512;
      #pragma unroll
      for (int cf = 0; cf < NCF; cf++) {
        short8 aH = *(const short8*)&fH[(size_t)cf * 512];
        short8 aL = *(const short8*)&fL[(size_t)cf * 512];
        #pragma unroll
        for (int pl = 0; pl < 4; pl++)
          acc[pl][cf] = __builtin_amdgcn_mfma_f32_16x16x32_bf16(aH, bh[pl], acc[pl][cf], 0, 0, 0);
        #pragma unroll
        for (int pl = 0; pl < 4; pl++)
          acc[pl][cf] = __builtin_amdgcn_mfma_f32_16x16x32_bf16(aH, bl[pl], acc[pl][cf], 0, 0, 0);
        #pragma unroll
        for (int pl = 0; pl < 4; pl++)
          acc[pl][cf] = __builtin_amdgcn_mfma_f32_16x16x32_bf16(aL, bh[pl], acc[pl][cf], 0, 0, 0);
      }
    }
  }

  const int co_l = (lane >> 4) * 4;
  if (EPI == 0) {
    #pragma unroll
    for (int pl = 0; pl < 4; pl++) {
      size_t pp = (size_t)((gy0 + pl + 1) * PITCH + gx0 + (lane & 15) + 1);
      u16* ob = out_hl + ((size_t)b * PADPX + pp) * 128;
      #pragma unroll
      for (int cf = 0; cf < NCF; cf++) {
        int c0 = (cog * NCF + cf) * 16 + co_l;
        u16 hbuf[4], lbuf[4];
        #pragma unroll
        for (int r = 0; r < 4; r++) {
          float v = acc[pl][cf][r] + bias[c0 + r];
          v = (v >= 0.f) ? v : 0.1f * v;
          u16 hi = bf16_rne(v);
          hbuf[r] = hi;
          lbuf[r] = bf16_rne(v - bf16f(hi));
        }
        *(uint2*)&ob[c0] = *(uint2*)hbuf;
        *(uint2*)&ob[64 + c0] = *(uint2*)lbuf;
      }
    }
  } else {
    #pragma unroll
    for (int pl = 0; pl < 4; pl++) {
      size_t pix = (size_t)(gy0 + pl) * Ww + gx0 + (lane & 15);
      float fl0 = flow[((size_t)b * 2 + 0) * HW + pix];
      float fl1 = flow[((size_t)b * 2 + 1) * HW + pix];
      #pragma unroll
      for (int cf = 0; cf < NCF; cf++) {
        int c0 = (cog * NCF + cf) * 16 + co_l;
        #pragma unroll
        for (int r = 0; r < 4; r++) {
          int cc = c0 + r;
          float v = acc[pl][cf][r] + bias[cc];
          if (cc < 288) {
            float e = __expf(2.f * v);
            float t = 1.f - 2.f * __builtin_amdgcn_rcpf(e + 1.f);
            offb[((size_t)b * 288 + cc) * HW + pix] = 10.f * t + ((cc & 1) ? fl0 : fl1);
          } else {
            mskb[((size_t)b * 144 + (cc - 288)) * HW + pix] =
                __builtin_amdgcn_rcpf(1.f + __expf(-v));
          }
        }
      }
    }
  }
}

// ---------------- dcn sampling: build bf16 im2col cols[b][18][px][32] ----------------
__global__ __launch_bounds__(256) void dcn_sample_k(
    const float* __restrict__ xt, const float* __restrict__ off,
    const float* __restrict__ msk, u16* __restrict__ cols)
{
  const int tid = threadIdx.x;
  const int px = blockIdx.x * 256 + tid;
  const int b = blockIdx.y >> 4, dg = blockIdx.y & 15;
  const int y = px >> 7, x = px & 127;
  const float* offp = off + ((size_t)b * 288 + dg * 18) * HW + px;
  const float* mp   = msk + ((size_t)b * 144 + dg * 9) * HW + px;
  const float4* xp4 = (const float4*)xt + (size_t)(b * 16 + dg) * HW;
  const int s = dg >> 3;
  u16* cbase = cols + (size_t)b * 18 * HW * 32 + (size_t)px * 32 + (dg & 7) * 4;

  #pragma unroll
  for (int k = 0; k < 9; k++) {
    float dyv = offp[(size_t)(2 * k) * HW];
    float dxv = offp[(size_t)(2 * k + 1) * HW];
    float mv  = mp[(size_t)k * HW];
    float py  = (float)(y - 1 + k / 3) + dyv;
    float pxx = (float)(x - 1 + (k % 3)) + dxv;
    float y0f = floorf(py), x0f = floorf(pxx);
    float wy = py - y0f, wx = pxx - x0f;
    int yi = (int)y0f, xi = (int)x0f;
    bool vy0 = (yi >= 0) & (yi < Hh);
    bool vy1 = (yi + 1 >= 0) & (yi + 1 < Hh);
    bool vx0 = (xi >= 0) & (xi < Ww);
    bool vx1 = (xi + 1 >= 0) & (xi + 1 < Ww);
    int y0c = min(max(yi, 0), Hh - 1), y1c = min(max(yi + 1, 0), Hh - 1);
    int x0c = min(max(xi, 0), Ww - 1), x1c = min(max(xi + 1, 0), Ww - 1);
    float w00 = (vy0 && vx0) ? (1.f - wy) * (1.f - wx) : 0.f;
    float w01 = (vy0 && vx1) ? (1.f - wy) * wx : 0.f;
    float w10 = (vy1 && vx0) ? wy * (1.f - wx) : 0.f;
    float w11 = (vy1 && vx1) ? wy * wx : 0.f;
    w00 *= mv; w01 *= mv; w10 *= mv; w11 *= mv;
    float4 s00 = xp4[y0c * Ww + x0c];
    float4 s01 = xp4[y0c * Ww + x1c];
    float4 s10 = xp4[y1c * Ww + x0c];
    float4 s11 = xp4[y1c * Ww + x1c];
    u16 buf[4];
    buf[0] = bf16_rne(s00.x * w00 + s01.x * w01 + s10.x * w10 + s11.x * w11);
    buf[1] = bf16_rne(s00.y * w00 + s01.y * w01 + s10.y * w10 + s11.y * w11);
    buf[2] = bf16_rne(s00.z * w00 + s01.z * w01 + s10.z * w10 + s11.z * w11);
    buf[3] = bf16_rne(s00.w * w00 + s01.w * w01 + s10.w * w10 + s11.w * w11);
    *(uint2*)&cbase[(size_t)(k * 2 + s) * HW * 32] = *(uint2*)buf;
  }
}

// ---------------- dcn GEMM: out[b,64co,px] = W[64,576] @ cols, 2-pass (WH, WL) ----------------
__global__ __launch_bounds__(256) void dcn_gemm_k(
    const u16* __restrict__ cols, const u16* __restrict__ wtd,
    const float* __restrict__ bias, float* __restrict__ out)
{
  const int tid = threadIdx.x;
  const int lane = tid & 63, wave = tid >> 6;
  const int b = blockIdx.x >> 8;
  const int px0 = (blockIdx.x & 255) * 64 + wave * 16;

  f32x4 acc[4];
  #pragma unroll
  for (int f = 0; f < 4; f++) acc[f] = (f32x4)0.f;

  const u16* cb = cols + (size_t)b * 18 * HW * 32
                  + ((size_t)px0 + (lane & 15)) * 32 + (lane >> 4) * 8;
  const u16* wb = wtd + (size_t)lane * 8;

  for (int ch = 0; ch < 18; ch++) {
    short8 bh = *(const short8*)&cb[(size_t)ch * HW * 32];
    const u16* wc = wb + (size_t)ch * 8 * 512;
    #pragma unroll
    for (int f = 0; f < 4; f++) {
      short8 aH = *(const short8*)&wc[(size_t)f * 512];
      short8 aL = *(const short8*)&wc[(size_t)(4 + f) * 512];
      acc[f] = __builtin_amdgcn_mfma_f32_16x16x32_bf16(aH, bh, acc[f], 0, 0, 0);
      acc[f] = __builtin_amdgcn_mfma_f32_16x16x32_bf16(aL, bh, acc[f], 0, 0, 0);
    }
  }

  const int pxo = px0 + (lane & 15);
  #pragma unroll
  for (int f = 0; f < 4; f++) {
    #pragma unroll
    for (int r = 0; r < 4; r++) {
      int co = f * 16 + (lane >> 4) * 4 + r;
      out[((size_t)b * 64 + co) * HW + pxo] = acc[f][r] + bias[co];
    }
  }
}

// ---------------- launch ----------------
extern "C" void kernel_launch(void* const* d_in, const int* in_sizes, int n_in,
                              void* d_out, int out_size, void* d_ws, size_t ws_size,
                              hipStream_t stream) {
  const float* x    = (const float*)d_in[0];
  const float* cond = (const float*)d_in[1];
  const float* flow = (const float*)d_in[2];
  const float* w1 = (const float*)d_in[3];
  const float* b1 = (const float*)d_in[4];
  const float* w2 = (const float*)d_in[5];
  const float* b2 = (const float*)d_in[6];
  const float* w3 = (const float*)d_in[7];
  const float* b3 = (const float*)d_in[8];
  const float* w4 = (const float*)d_in[9];
  const float* b4 = (const float*)d_in[10];
  const float* wD = (const float*)d_in[11];
  const float* bD = (const float*)d_in[12];
  float* out = (float*)d_out;
  const int B = 2;

  char* ws = (char*)d_ws;
  // region A: cond_hl + hA + hB, later aliased by cols (all dead by sample time)
  u16* cols    = (u16*)ws;                       // 37,748,736 B
  u16* cond_hl = (u16*)ws;                       // 2*16900*320*2 = 21,632,000 B
  u16* hA = (u16*)(ws + 21632000);               // 2*16900*128*2 =  8,652,800 B
  u16* hB = (u16*)(ws + 30284800);               //                  8,652,800 B
  char* pw = ws + 38937600;
  float* offb = (float*)pw;          pw += 37748736;
  float* mskb = (float*)pw;          pw += 18874368;
  float* xt   = (float*)pw;          pw += 8388608;
  u16*   wt1  = (u16*)pw;            pw += 368640;
  u16*   wt2  = (u16*)pw;            pw += 147456;
  u16*   wt3  = (u16*)pw;            pw += 147456;
  u16*   wt4  = (u16*)pw;            pw += 995328;
  u16*   wtd  = (u16*)pw;            pw += 147456;

  // halo zeroing + prep + weight transposes
  zero_edge_k<<<dim3((516 * 40 + 255) / 256, B), 256, 0, stream>>>(cond_hl, 320);
  zero_edge_k<<<dim3((516 * 16 + 255) / 256, B), 256, 0, stream>>>(hA, 128);
  zero_edge_k<<<dim3((516 * 16 + 255) / 256, B), 256, 0, stream>>>(hB, 128);
  prep_cond_k<<<dim3(HW / 256, B), 256, 0, stream>>>(cond, cond_hl);
  xtrans_k<<<dim3(B * 16 * HW / 256), 256, 0, stream>>>(x, xt, B);
  wtrans_mfma_k<<<dim3((9 * 5 * 2 * 4 * 64 + 255) / 256), 256, 0, stream>>>(w1, wt1, 133, 5, 4);
  wtrans_mfma_k<<<dim3((9 * 2 * 2 * 4 * 64 + 255) / 256), 256, 0, stream>>>(w2, wt2, 64, 2, 4);
  wtrans_mfma_k<<<dim3((9 * 2 * 2 * 4 * 64 + 255) / 256), 256, 0, stream>>>(w3, wt3, 64, 2, 4);
  wtrans_mfma_k<<<dim3((9 * 2 * 2 * 27 * 64 + 255) / 256), 256, 0, stream>>>(w4, wt4, 64, 2, 27);
  wtrans_dcn_mfma_k<<<dim3((18 * 2 * 4 * 64 + 255) / 256), 256, 0, stream>>>(wD, wtd);

  // convs (direct-from-global MFMA), block=128, tile 16x8
  conv_direct_k<160, 5, 1, 4, 0><<<dim3(8, 16, B * 4), 128, 0, stream>>>(
      cond_hl, wt1, b1, hA, nullptr, nullptr, nullptr, 4);
  conv_direct_k<64, 2, 1, 4, 0><<<dim3(8, 16, B * 4), 128, 0, stream>>>(
      hA, wt2, b2, hB, nullptr, nullptr, nullptr, 4);
  conv_direct_k<64, 2, 1, 4, 0><<<dim3(8, 16, B * 4), 128, 0, stream>>>(
      hB, wt3, b3, hA, nullptr, nullptr, nullptr, 4);
  conv_direct_k<64, 2, 3, 27, 2><<<dim3(8, 16, B * 9), 128, 0, stream>>>(
      hA, wt4, b4, nullptr, offb, mskb, flow, 9);

  // deformable conv: sample -> im2col (bf16) -> MFMA GEMM
  dcn_sample_k<<<dim3(HW / 256, B * 16), 256, 0, stream>>>(xt, offb, mskb, cols);
  dcn_gemm_k<<<dim3(512), 256, 0, stream>>>(cols, wtd, bD, out);
}

// Round 5
// 208.312 us; speedup vs baseline: 1.5197x; 1.5197x over previous
//
#include <hip/hip_runtime.h>
#include <math.h>

#define Hh 128
#define Ww 128
#define HW (128*128)
#define PITCH 130
#define PADPX (130*130)

typedef unsigned short u16;
typedef unsigned int uint;
typedef _Float16 f16;
typedef __attribute__((ext_vector_type(8))) _Float16 f16x8;
typedef __attribute__((ext_vector_type(4))) float f32x4;

// ---------------- zero halo edges of padded NHWC f16 buffer ----------------
__global__ __launch_bounds__(256) void zero_edge_k(u16* __restrict__ buf, int cu16) {
  int per_px = cu16 >> 3;           // uint4 chunks per pixel
  int total = 516 * per_px;
  int idx = blockIdx.x * 256 + threadIdx.x;
  int b = blockIdx.y;
  if (idx >= total) return;
  int e = idx / per_px, q = idx - e * per_px;
  int y, x;
  if (e < 130)      { y = 0;   x = e; }
  else if (e < 260) { y = 129; x = e - 130; }
  else { int j = e - 260; y = 1 + (j >> 1); x = (j & 1) ? 129 : 0; }
  *(uint4*)&buf[((size_t)b * PADPX + (size_t)(y * PITCH + x)) * cu16 + q * 8] =
      make_uint4(0, 0, 0, 0);
}

// ---------------- prep: cond [B][133][HW] f32 -> padded NHWC f16 [B][PADPX][160] ----------------
__global__ __launch_bounds__(256) void prep_cond_k(const float* __restrict__ cond,
                                                   f16* __restrict__ out) {
  int p = blockIdx.x * 256 + threadIdx.x;
  int b = blockIdx.y;
  int y = p >> 7, x = p & 127;
  const float* cb = cond + (size_t)b * 133 * HW + p;
  f16* ob = out + ((size_t)b * PADPX + (size_t)((y + 1) * PITCH + x + 1)) * 160;
  for (int c = 0; c < 160; c += 8) {
    f16 buf[8];
    #pragma unroll
    for (int j = 0; j < 8; j++) {
      float v = (c + j < 133) ? cb[(size_t)(c + j) * HW] : 0.f;
      buf[j] = (f16)v;
    }
    *(uint4*)&ob[c] = *(uint4*)buf;
  }
}

// ---------------- conv weight -> f16 MFMA A-frags: frag = (t*NC + c)*NCOF + f ----------------
__global__ __launch_bounds__(256) void wtrans_mfma_k(const float* __restrict__ w,
                                                     f16* __restrict__ wt,
                                                     int CIN, int NC, int NCOF) {
  int idx = blockIdx.x * 256 + threadIdx.x;
  int total = 9 * NC * NCOF * 64;
  if (idx >= total) return;
  int lane = idx & 63;
  int frag = idx >> 6;
  int f = frag % NCOF;
  int rest = frag / NCOF;
  int c = rest % NC;
  int t = rest / NC;
  int co = f * 16 + (lane & 15);
  int ci0 = c * 32 + (lane >> 4) * 8;
  f16 buf[8];
  #pragma unroll
  for (int j = 0; j < 8; j++) {
    int ci = ci0 + j;
    buf[j] = (f16)((ci < CIN) ? w[((size_t)co * CIN + ci) * 9 + t] : 0.f);
  }
  *(uint4*)&wt[(size_t)idx * 8] = *(uint4*)buf;
}

// ---------------- dcn weight -> f16 A-frags over K=576 (ci = k*64 + dg*4 + c) ----------------
__global__ __launch_bounds__(256) void wtrans_dcn_mfma_k(const float* __restrict__ w,
                                                         f16* __restrict__ wt) {
  int idx = blockIdx.x * 256 + threadIdx.x;
  if (idx >= 18 * 4 * 64) return;
  int lane = idx & 63;
  int frag = idx >> 6;
  int f = frag & 3;
  int chunk = frag >> 2;
  int co = f * 16 + (lane & 15);
  int ci0 = chunk * 32 + (lane >> 4) * 8;
  f16 buf[8];
  #pragma unroll
  for (int j = 0; j < 8; j++) {
    int ci = ci0 + j;
    int k = ci >> 6, cig = ci & 63;
    buf[j] = (f16)w[((size_t)co * 64 + cig) * 9 + k];
  }
  *(uint4*)&wt[(size_t)idx * 8] = *(uint4*)buf;
}

// x [B][64][H][W] -> xt [B][16][H][W][4]
__global__ __launch_bounds__(256) void xtrans_k(const float* __restrict__ x,
                                                float* __restrict__ xt, int B) {
  int idx = blockIdx.x * 256 + threadIdx.x;
  int total = B * 16 * HW;
  if (idx >= total) return;
  int b = idx / (16 * HW);
  int r = idx % (16 * HW);
  int dg = r / HW, p = r % HW;
  const float* xb = x + ((size_t)b * 64 + dg * 4) * HW + p;
  float4 v;
  v.x = xb[0]; v.y = xb[HW]; v.z = xb[2 * HW]; v.w = xb[3 * HW];
  ((float4*)xt)[idx] = v;
}

// ---------------- conv3x3 via f16 MFMA, single pass, LDS-staged ----------------
// in: padded NHWC f16 [b][PADPX][CINP]. 16x16 px tile, 4 waves (4 px-rows each).
// LDS: one 32-ci chunk [324 px][40 u16] (80B pitch, 16B-aligned slots).
template<int CINP, int NC, int NCF, int NCOF, int EPI>
__global__ __launch_bounds__(256, 4) void conv_f16_k(
    const f16* __restrict__ in, const f16* __restrict__ wt,
    const float* __restrict__ bias, f16* __restrict__ out,
    float* __restrict__ offb, float* __restrict__ mskb,
    const float* __restrict__ flow, int cogroups)
{
  __shared__ u16 lds[324 * 40];
  const int tid = threadIdx.x;
  const int lane = tid & 63, wave = tid >> 6;
  const int b = blockIdx.z / cogroups, cog = blockIdx.z % cogroups;
  const int gx0 = blockIdx.x * 16, gy0 = blockIdx.y * 16;

  f32x4 acc[4][NCF];
  #pragma unroll
  for (int i = 0; i < 4; i++)
    #pragma unroll
    for (int j = 0; j < NCF; j++) acc[i][j] = (f32x4)0.f;

  const f16* inb = in + (size_t)b * PADPX * CINP;

  for (int c = 0; c < NC; c++) {
    __syncthreads();
    // stage 18x18 halo x 32 ci (f16): 324 px * 4 quads of 16B
    for (int i = tid; i < 1296; i += 256) {
      int pidx = i >> 2, q = i & 3;
      int py = pidx / 18, px = pidx - py * 18;
      size_t gp = (size_t)((gy0 + py) * PITCH + gx0 + px);
      uint4 v = *(const uint4*)&inb[gp * CINP + c * 32 + q * 8];
      *(uint4*)&lds[pidx * 40 + q * 8] = v;
    }
    __syncthreads();

    #pragma unroll
    for (int tap = 0; tap < 9; tap++) {
      const int dy = tap / 3, dx = tap % 3;
      f16x8 bfrag[4];
      #pragma unroll
      for (int pl = 0; pl < 4; pl++) {
        int pidx_r = (wave * 4 + pl + dy) * 18 + (lane & 15) + dx;
        bfrag[pl] = *(const f16x8*)&lds[pidx_r * 40 + (lane >> 4) * 8];
      }
      const f16* fA = wt + (((size_t)(tap * NC + c)) * NCOF + cog * NCF) * 512
                      + (size_t)lane * 8;
      #pragma unroll
      for (int cf = 0; cf < NCF; cf++) {
        f16x8 a = *(const f16x8*)&fA[(size_t)cf * 512];
        #pragma unroll
        for (int pl = 0; pl < 4; pl++)
          acc[pl][cf] = __builtin_amdgcn_mfma_f32_16x16x32_f16(a, bfrag[pl], acc[pl][cf], 0, 0, 0);
      }
    }
  }

  const int co_l = (lane >> 4) * 4;
  if (EPI == 0) {
    #pragma unroll
    for (int pl = 0; pl < 4; pl++) {
      size_t pp = (size_t)((gy0 + wave * 4 + pl + 1) * PITCH + gx0 + (lane & 15) + 1);
      f16* ob = out + ((size_t)b * PADPX + pp) * (NCOF * 16);
      #pragma unroll
      for (int cf = 0; cf < NCF; cf++) {
        int c0 = (cog * NCF + cf) * 16 + co_l;
        f16 buf[4];
        #pragma unroll
        for (int r = 0; r < 4; r++) {
          float v = acc[pl][cf][r] + bias[c0 + r];
          buf[r] = (f16)((v >= 0.f) ? v : 0.1f * v);
        }
        *(uint2*)&ob[c0] = *(uint2*)buf;
      }
    }
  } else {
    #pragma unroll
    for (int pl = 0; pl < 4; pl++) {
      size_t pix = (size_t)(gy0 + wave * 4 + pl) * Ww + gx0 + (lane & 15);
      float fl0 = flow[((size_t)b * 2 + 0) * HW + pix];
      float fl1 = flow[((size_t)b * 2 + 1) * HW + pix];
      #pragma unroll
      for (int cf = 0; cf < NCF; cf++) {
        int c0 = (cog * NCF + cf) * 16 + co_l;
        #pragma unroll
        for (int r = 0; r < 4; r++) {
          int cc = c0 + r;
          float v = acc[pl][cf][r] + bias[cc];
          if (cc < 288) {
            float e = __expf(2.f * v);
            float t = 1.f - 2.f * __builtin_amdgcn_rcpf(e + 1.f);
            offb[((size_t)b * 288 + cc) * HW + pix] = 10.f * t + ((cc & 1) ? fl0 : fl1);
          } else {
            mskb[((size_t)b * 144 + (cc - 288)) * HW + pix] =
                __builtin_amdgcn_rcpf(1.f + __expf(-v));
          }
        }
      }
    }
  }
}

// ---------------- dcn sampling: build f16 im2col cols[b][18][px][32] ----------------
// ci = k*64 + dg*4 + c -> chunk = k*2 + (dg>=8), pos = (dg&7)*4 + c
__global__ __launch_bounds__(256) void dcn_sample_k(
    const float* __restrict__ xt, const float* __restrict__ off,
    const float* __restrict__ msk, f16* __restrict__ cols)
{
  const int tid = threadIdx.x;
  const int px = blockIdx.x * 256 + tid;
  const int b = blockIdx.y >> 4, dg = blockIdx.y & 15;
  const int y = px >> 7, x = px & 127;
  const float* offp = off + ((size_t)b * 288 + dg * 18) * HW + px;
  const float* mp   = msk + ((size_t)b * 144 + dg * 9) * HW + px;
  const float4* xp4 = (const float4*)xt + (size_t)(b * 16 + dg) * HW;
  const int s = dg >> 3;
  f16* cbase = cols + (size_t)b * 18 * HW * 32 + (size_t)px * 32 + (dg & 7) * 4;

  #pragma unroll
  for (int k = 0; k < 9; k++) {
    float dyv = offp[(size_t)(2 * k) * HW];
    float dxv = offp[(size_t)(2 * k + 1) * HW];
    float mv  = mp[(size_t)k * HW];
    float py  = (float)(y - 1 + k / 3) + dyv;
    float pxx = (float)(x - 1 + (k % 3)) + dxv;
    float y0f = floorf(py), x0f = floorf(pxx);
    float wy = py - y0f, wx = pxx - x0f;
    int yi = (int)y0f, xi = (int)x0f;
    bool vy0 = (yi >= 0) & (yi < Hh);
    bool vy1 = (yi + 1 >= 0) & (yi + 1 < Hh);
    bool vx0 = (xi >= 0) & (xi < Ww);
    bool vx1 = (xi + 1 >= 0) & (xi + 1 < Ww);
    int y0c = min(max(yi, 0), Hh - 1), y1c = min(max(yi + 1, 0), Hh - 1);
    int x0c = min(max(xi, 0), Ww - 1), x1c = min(max(xi + 1, 0), Ww - 1);
    float w00 = (vy0 && vx0) ? (1.f - wy) * (1.f - wx) : 0.f;
    float w01 = (vy0 && vx1) ? (1.f - wy) * wx : 0.f;
    float w10 = (vy1 && vx0) ? wy * (1.f - wx) : 0.f;
    float w11 = (vy1 && vx1) ? wy * wx : 0.f;
    w00 *= mv; w01 *= mv; w10 *= mv; w11 *= mv;
    float4 s00 = xp4[y0c * Ww + x0c];
    float4 s01 = xp4[y0c * Ww + x1c];
    float4 s10 = xp4[y1c * Ww + x0c];
    float4 s11 = xp4[y1c * Ww + x1c];
    f16 buf[4];
    buf[0] = (f16)(s00.x * w00 + s01.x * w01 + s10.x * w10 + s11.x * w11);
    buf[1] = (f16)(s00.y * w00 + s01.y * w01 + s10.y * w10 + s11.y * w11);
    buf[2] = (f16)(s00.z * w00 + s01.z * w01 + s10.z * w10 + s11.z * w11);
    buf[3] = (f16)(s00.w * w00 + s01.w * w01 + s10.w * w10 + s11.w * w11);
    *(uint2*)&cbase[(size_t)(k * 2 + s) * HW * 32] = *(uint2*)buf;
  }
}

// ---------------- dcn GEMM: out[b,64co,px] = W[64,576] @ cols, single f16 pass ----------------
__global__ __launch_bounds__(256) void dcn_gemm_k(
    const f16* __restrict__ cols, const f16* __restrict__ wtd,
    const float* __restrict__ bias, float* __restrict__ out)
{
  const int tid = threadIdx.x;
  const int lane = tid & 63, wave = tid >> 6;
  const int b = blockIdx.x >> 8;
  const int px0 = (blockIdx.x & 255) * 64 + wave * 16;

  f32x4 acc[4];
  #pragma unroll
  for (int f = 0; f < 4; f++) acc[f] = (f32x4)0.f;

  const f16* cb = cols + (size_t)b * 18 * HW * 32
                  + ((size_t)px0 + (lane & 15)) * 32 + (lane >> 4) * 8;
  const f16* wb = wtd + (size_t)lane * 8;

  #pragma unroll 3
  for (int ch = 0; ch < 18; ch++) {
    f16x8 bh = *(const f16x8*)&cb[(size_t)ch * HW * 32];
    const f16* wc = wb + (size_t)ch * 4 * 512;
    #pragma unroll
    for (int f = 0; f < 4; f++) {
      f16x8 a = *(const f16x8*)&wc[(size_t)f * 512];
      acc[f] = __builtin_amdgcn_mfma_f32_16x16x32_f16(a, bh, acc[f], 0, 0, 0);
    }
  }

  const int pxo = px0 + (lane & 15);
  #pragma unroll
  for (int f = 0; f < 4; f++) {
    #pragma unroll
    for (int r = 0; r < 4; r++) {
      int co = f * 16 + (lane >> 4) * 4 + r;
      out[((size_t)b * 64 + co) * HW + pxo] = acc[f][r] + bias[co];
    }
  }
}

// ---------------- launch ----------------
extern "C" void kernel_launch(void* const* d_in, const int* in_sizes, int n_in,
                              void* d_out, int out_size, void* d_ws, size_t ws_size,
                              hipStream_t stream) {
  const float* x    = (const float*)d_in[0];
  const float* cond = (const float*)d_in[1];
  const float* flow = (const float*)d_in[2];
  const float* w1 = (const float*)d_in[3];
  const float* b1 = (const float*)d_in[4];
  const float* w2 = (const float*)d_in[5];
  const float* b2 = (const float*)d_in[6];
  const float* w3 = (const float*)d_in[7];
  const float* b3 = (const float*)d_in[8];
  const float* w4 = (const float*)d_in[9];
  const float* b4 = (const float*)d_in[10];
  const float* wD = (const float*)d_in[11];
  const float* bD = (const float*)d_in[12];
  float* out = (float*)d_out;
  const int B = 2;

  char* ws = (char*)d_ws;
  // region A (37,748,736 B): condp + hA + hB during convs; aliased by cols afterwards
  f16* cols  = (f16*)ws;
  f16* condp = (f16*)ws;                         // 2*16900*160*2 = 10,816,000
  f16* hA = (f16*)(ws + 10816000);               // 2*16900*64*2  =  4,326,400
  f16* hB = (f16*)(ws + 15142400);               //                  4,326,400
  char* pw = ws + 37748736;
  float* offb = (float*)pw;          pw += 37748736;
  float* mskb = (float*)pw;          pw += 18874368;
  float* xt   = (float*)pw;          pw += 8388608;
  f16*   wt1  = (f16*)pw;            pw += 184320;   // 9*5*4 frags * 1KB
  f16*   wt2  = (f16*)pw;            pw += 73728;    // 9*2*4
  f16*   wt3  = (f16*)pw;            pw += 73728;
  f16*   wt4  = (f16*)pw;            pw += 497664;   // 9*2*27
  f16*   wtd  = (f16*)pw;            pw += 73728;    // 18*4

  // halo zeroing + prep + weight transposes
  zero_edge_k<<<dim3((516 * 20 + 255) / 256, B), 256, 0, stream>>>((u16*)condp, 160);
  zero_edge_k<<<dim3((516 * 8 + 255) / 256, B), 256, 0, stream>>>((u16*)hA, 64);
  zero_edge_k<<<dim3((516 * 8 + 255) / 256, B), 256, 0, stream>>>((u16*)hB, 64);
  prep_cond_k<<<dim3(HW / 256, B), 256, 0, stream>>>(cond, condp);
  xtrans_k<<<dim3(B * 16 * HW / 256), 256, 0, stream>>>(x, xt, B);
  wtrans_mfma_k<<<dim3((9 * 5 * 4 * 64 + 255) / 256), 256, 0, stream>>>(w1, wt1, 133, 5, 4);
  wtrans_mfma_k<<<dim3((9 * 2 * 4 * 64 + 255) / 256), 256, 0, stream>>>(w2, wt2, 64, 2, 4);
  wtrans_mfma_k<<<dim3((9 * 2 * 4 * 64 + 255) / 256), 256, 0, stream>>>(w3, wt3, 64, 2, 4);
  wtrans_mfma_k<<<dim3((9 * 2 * 27 * 64 + 255) / 256), 256, 0, stream>>>(w4, wt4, 64, 2, 27);
  wtrans_dcn_mfma_k<<<dim3((18 * 4 * 64 + 255) / 256), 256, 0, stream>>>(wD, wtd);

  // convs (f16 MFMA, LDS-staged)
  conv_f16_k<160, 5, 1, 4, 0><<<dim3(8, 8, B * 4), 256, 0, stream>>>(
      condp, wt1, b1, hA, nullptr, nullptr, nullptr, 4);
  conv_f16_k<64, 2, 1, 4, 0><<<dim3(8, 8, B * 4), 256, 0, stream>>>(
      hA, wt2, b2, hB, nullptr, nullptr, nullptr, 4);
  conv_f16_k<64, 2, 1, 4, 0><<<dim3(8, 8, B * 4), 256, 0, stream>>>(
      hB, wt3, b3, hA, nullptr, nullptr, nullptr, 4);
  conv_f16_k<64, 2, 3, 27, 2><<<dim3(8, 8, B * 9), 256, 0, stream>>>(
      hA, wt4, b4, nullptr, offb, mskb, flow, 9);

  // deformable conv: sample -> f16 im2col -> single-pass MFMA GEMM
  dcn_sample_k<<<dim3(HW / 256, B * 16), 256, 0, stream>>>(xt, offb, mskb, cols);
  dcn_gemm_k<<<dim3(512), 256, 0, stream>>>(cols, wtd, bD, out);
}

// Round 6
// 203.774 us; speedup vs baseline: 1.5535x; 1.0223x over previous
//
#include <hip/hip_runtime.h>
#include <math.h>

#define Hh 128
#define Ww 128
#define HW (128*128)
#define PITCH 130
#define PADPX (130*130)

typedef unsigned short u16;
typedef unsigned int uint;
typedef _Float16 f16;
typedef __attribute__((ext_vector_type(8))) _Float16 f16x8;
typedef __attribute__((ext_vector_type(4))) _Float16 f16x4;
typedef __attribute__((ext_vector_type(4))) float f32x4;

// ---------------- zero halo edges of padded NHWC f16 buffer ----------------
__global__ __launch_bounds__(256) void zero_edge_k(u16* __restrict__ buf, int cu16) {
  int per_px = cu16 >> 3;           // uint4 chunks per pixel
  int total = 516 * per_px;
  int idx = blockIdx.x * 256 + threadIdx.x;
  int b = blockIdx.y;
  if (idx >= total) return;
  int e = idx / per_px, q = idx - e * per_px;
  int y, x;
  if (e < 130)      { y = 0;   x = e; }
  else if (e < 260) { y = 129; x = e - 130; }
  else { int j = e - 260; y = 1 + (j >> 1); x = (j & 1) ? 129 : 0; }
  *(uint4*)&buf[((size_t)b * PADPX + (size_t)(y * PITCH + x)) * cu16 + q * 8] =
      make_uint4(0, 0, 0, 0);
}

// ---------------- prep: cond [B][133][HW] f32 -> padded NHWC f16 [B][PADPX][160] ----------------
__global__ __launch_bounds__(256) void prep_cond_k(const float* __restrict__ cond,
                                                   f16* __restrict__ out) {
  int p = blockIdx.x * 256 + threadIdx.x;
  int b = blockIdx.y;
  int y = p >> 7, x = p & 127;
  const float* cb = cond + (size_t)b * 133 * HW + p;
  f16* ob = out + ((size_t)b * PADPX + (size_t)((y + 1) * PITCH + x + 1)) * 160;
  for (int c = 0; c < 160; c += 8) {
    f16 buf[8];
    #pragma unroll
    for (int j = 0; j < 8; j++) {
      float v = (c + j < 133) ? cb[(size_t)(c + j) * HW] : 0.f;
      buf[j] = (f16)v;
    }
    *(uint4*)&ob[c] = *(uint4*)buf;
  }
}

// ---------------- conv weight -> f16 MFMA A-frags: frag = (t*NC + c)*NCOF + f ----------------
__global__ __launch_bounds__(256) void wtrans_mfma_k(const float* __restrict__ w,
                                                     f16* __restrict__ wt,
                                                     int CIN, int NC, int NCOF) {
  int idx = blockIdx.x * 256 + threadIdx.x;
  int total = 9 * NC * NCOF * 64;
  if (idx >= total) return;
  int lane = idx & 63;
  int frag = idx >> 6;
  int f = frag % NCOF;
  int rest = frag / NCOF;
  int c = rest % NC;
  int t = rest / NC;
  int co = f * 16 + (lane & 15);
  int ci0 = c * 32 + (lane >> 4) * 8;
  f16 buf[8];
  #pragma unroll
  for (int j = 0; j < 8; j++) {
    int ci = ci0 + j;
    buf[j] = (f16)((ci < CIN) ? w[((size_t)co * CIN + ci) * 9 + t] : 0.f);
  }
  *(uint4*)&wt[(size_t)idx * 8] = *(uint4*)buf;
}

// ---------------- dcn weight -> f16 A-frags over K=576 (ci = k*64 + dg*4 + c) ----------------
__global__ __launch_bounds__(256) void wtrans_dcn_mfma_k(const float* __restrict__ w,
                                                         f16* __restrict__ wt) {
  int idx = blockIdx.x * 256 + threadIdx.x;
  if (idx >= 18 * 4 * 64) return;
  int lane = idx & 63;
  int frag = idx >> 6;
  int f = frag & 3;
  int chunk = frag >> 2;
  int co = f * 16 + (lane & 15);
  int ci0 = chunk * 32 + (lane >> 4) * 8;
  f16 buf[8];
  #pragma unroll
  for (int j = 0; j < 8; j++) {
    int ci = ci0 + j;
    int k = ci >> 6, cig = ci & 63;
    buf[j] = (f16)w[((size_t)co * 64 + cig) * 9 + k];
  }
  *(uint4*)&wt[(size_t)idx * 8] = *(uint4*)buf;
}

// x [B][64][H][W] f32 -> xt [B][16][H][W][4] f16
__global__ __launch_bounds__(256) void xtrans_k(const float* __restrict__ x,
                                                f16* __restrict__ xt, int B) {
  int idx = blockIdx.x * 256 + threadIdx.x;
  int total = B * 16 * HW;
  if (idx >= total) return;
  int b = idx / (16 * HW);
  int r = idx % (16 * HW);
  int dg = r / HW, p = r % HW;
  const float* xb = x + ((size_t)b * 64 + dg * 4) * HW + p;
  f16 buf[4];
  buf[0] = (f16)xb[0]; buf[1] = (f16)xb[HW];
  buf[2] = (f16)xb[2 * HW]; buf[3] = (f16)xb[3 * HW];
  *(uint2*)&xt[(size_t)idx * 4] = *(uint2*)buf;
}

// ---------------- conv3x3 via f16 MFMA, single pass, LDS-staged ----------------
template<int CINP, int NC, int NCF, int NCOF, int EPI>
__global__ __launch_bounds__(256, 4) void conv_f16_k(
    const f16* __restrict__ in, const f16* __restrict__ wt,
    const float* __restrict__ bias, f16* __restrict__ out,
    float* __restrict__ offb, f16* __restrict__ mskb,
    const float* __restrict__ flow, int cogroups)
{
  __shared__ u16 lds[324 * 40];
  const int tid = threadIdx.x;
  const int lane = tid & 63, wave = tid >> 6;
  const int b = blockIdx.z / cogroups, cog = blockIdx.z % cogroups;
  const int gx0 = blockIdx.x * 16, gy0 = blockIdx.y * 16;

  f32x4 acc[4][NCF];
  #pragma unroll
  for (int i = 0; i < 4; i++)
    #pragma unroll
    for (int j = 0; j < NCF; j++) acc[i][j] = (f32x4)0.f;

  const f16* inb = in + (size_t)b * PADPX * CINP;

  for (int c = 0; c < NC; c++) {
    __syncthreads();
    for (int i = tid; i < 1296; i += 256) {
      int pidx = i >> 2, q = i & 3;
      int py = pidx / 18, px = pidx - py * 18;
      size_t gp = (size_t)((gy0 + py) * PITCH + gx0 + px);
      uint4 v = *(const uint4*)&inb[gp * CINP + c * 32 + q * 8];
      *(uint4*)&lds[pidx * 40 + q * 8] = v;
    }
    __syncthreads();

    #pragma unroll
    for (int tap = 0; tap < 9; tap++) {
      const int dy = tap / 3, dx = tap % 3;
      f16x8 bfrag[4];
      #pragma unroll
      for (int pl = 0; pl < 4; pl++) {
        int pidx_r = (wave * 4 + pl + dy) * 18 + (lane & 15) + dx;
        bfrag[pl] = *(const f16x8*)&lds[pidx_r * 40 + (lane >> 4) * 8];
      }
      const f16* fA = wt + (((size_t)(tap * NC + c)) * NCOF + cog * NCF) * 512
                      + (size_t)lane * 8;
      #pragma unroll
      for (int cf = 0; cf < NCF; cf++) {
        f16x8 a = *(const f16x8*)&fA[(size_t)cf * 512];
        #pragma unroll
        for (int pl = 0; pl < 4; pl++)
          acc[pl][cf] = __builtin_amdgcn_mfma_f32_16x16x32_f16(a, bfrag[pl], acc[pl][cf], 0, 0, 0);
      }
    }
  }

  const int co_l = (lane >> 4) * 4;
  if (EPI == 0) {
    #pragma unroll
    for (int pl = 0; pl < 4; pl++) {
      size_t pp = (size_t)((gy0 + wave * 4 + pl + 1) * PITCH + gx0 + (lane & 15) + 1);
      f16* ob = out + ((size_t)b * PADPX + pp) * (NCOF * 16);
      #pragma unroll
      for (int cf = 0; cf < NCF; cf++) {
        int c0 = (cog * NCF + cf) * 16 + co_l;
        f16 buf[4];
        #pragma unroll
        for (int r = 0; r < 4; r++) {
          float v = acc[pl][cf][r] + bias[c0 + r];
          buf[r] = (f16)((v >= 0.f) ? v : 0.1f * v);
        }
        *(uint2*)&ob[c0] = *(uint2*)buf;
      }
    }
  } else {
    #pragma unroll
    for (int pl = 0; pl < 4; pl++) {
      size_t pix = (size_t)(gy0 + wave * 4 + pl) * Ww + gx0 + (lane & 15);
      float fl0 = flow[((size_t)b * 2 + 0) * HW + pix];
      float fl1 = flow[((size_t)b * 2 + 1) * HW + pix];
      #pragma unroll
      for (int cf = 0; cf < NCF; cf++) {
        int c0 = (cog * NCF + cf) * 16 + co_l;
        #pragma unroll
        for (int r = 0; r < 4; r++) {
          int cc = c0 + r;
          float v = acc[pl][cf][r] + bias[cc];
          if (cc < 288) {
            float e = __expf(2.f * v);
            float t = 1.f - 2.f * __builtin_amdgcn_rcpf(e + 1.f);
            offb[((size_t)b * 288 + cc) * HW + pix] = 10.f * t + ((cc & 1) ? fl0 : fl1);
          } else {
            mskb[((size_t)b * 144 + (cc - 288)) * HW + pix] =
                (f16)__builtin_amdgcn_rcpf(1.f + __expf(-v));
          }
        }
      }
    }
  }
}

// ---------------- dcn sampling: 16px x 16dg blocks, LDS transpose, coalesced cols writes ----
// cols[b][chunk=18][px][32], K = k*64 + dg*4 + c, chunk = K>>5
#define SPITCH 584
__global__ __launch_bounds__(256) void dcn_sample_k(
    const f16* __restrict__ xt, const float* __restrict__ off,
    const f16* __restrict__ msk, f16* __restrict__ cols)
{
  __shared__ u16 lds[16 * SPITCH];
  const int tid = threadIdx.x;
  const int pl = tid & 15, dg = tid >> 4;
  const int b = blockIdx.y;
  const int px = blockIdx.x * 16 + pl;
  const int y = px >> 7, x = px & 127;
  const float* offp = off + ((size_t)b * 288 + dg * 18) * HW + px;
  const f16*   mp   = msk + ((size_t)b * 144 + dg * 9) * HW + px;
  const f16*   xp   = xt + (size_t)(b * 16 + dg) * HW * 4;

  #pragma unroll
  for (int k = 0; k < 9; k++) {
    float dyv = offp[(size_t)(2 * k) * HW];
    float dxv = offp[(size_t)(2 * k + 1) * HW];
    float mv  = (float)mp[(size_t)k * HW];
    float py  = (float)(y - 1 + k / 3) + dyv;
    float pxx = (float)(x - 1 + (k % 3)) + dxv;
    float y0f = floorf(py), x0f = floorf(pxx);
    float wy = py - y0f, wx = pxx - x0f;
    int yi = (int)y0f, xi = (int)x0f;
    bool vy0 = (yi >= 0) & (yi < Hh);
    bool vy1 = (yi + 1 >= 0) & (yi + 1 < Hh);
    bool vx0 = (xi >= 0) & (xi < Ww);
    bool vx1 = (xi + 1 >= 0) & (xi + 1 < Ww);
    int y0c = min(max(yi, 0), Hh - 1), y1c = min(max(yi + 1, 0), Hh - 1);
    int x0c = min(max(xi, 0), Ww - 1), x1c = min(max(xi + 1, 0), Ww - 1);
    float w00 = (vy0 && vx0) ? (1.f - wy) * (1.f - wx) : 0.f;
    float w01 = (vy0 && vx1) ? (1.f - wy) * wx : 0.f;
    float w10 = (vy1 && vx0) ? wy * (1.f - wx) : 0.f;
    float w11 = (vy1 && vx1) ? wy * wx : 0.f;
    w00 *= mv; w01 *= mv; w10 *= mv; w11 *= mv;
    f16x4 s00 = *(const f16x4*)&xp[(y0c * Ww + x0c) * 4];
    f16x4 s01 = *(const f16x4*)&xp[(y0c * Ww + x1c) * 4];
    f16x4 s10 = *(const f16x4*)&xp[(y1c * Ww + x0c) * 4];
    f16x4 s11 = *(const f16x4*)&xp[(y1c * Ww + x1c) * 4];
    f16 buf[4];
    buf[0] = (f16)((float)s00.x * w00 + (float)s01.x * w01 + (float)s10.x * w10 + (float)s11.x * w11);
    buf[1] = (f16)((float)s00.y * w00 + (float)s01.y * w01 + (float)s10.y * w10 + (float)s11.y * w11);
    buf[2] = (f16)((float)s00.z * w00 + (float)s01.z * w01 + (float)s10.z * w10 + (float)s11.z * w11);
    buf[3] = (f16)((float)s00.w * w00 + (float)s01.w * w01 + (float)s10.w * w10 + (float)s11.w * w11);
    *(uint2*)&lds[pl * SPITCH + k * 64 + dg * 4] = *(uint2*)buf;
  }
  __syncthreads();

  // cooperative coalesced writeout: cols[b][ch][px0..15][32]
  const int px0 = blockIdx.x * 16;
  for (int i = tid; i < 1152; i += 256) {
    int ch = i >> 6, r = i & 63, p2 = r >> 2, q = r & 3;
    uint4 v = *(const uint4*)&lds[p2 * SPITCH + ch * 32 + q * 8];
    *(uint4*)&cols[(((size_t)b * 18 + ch) * HW + px0 + p2) * 32 + q * 8] = v;
  }
}

// ---------------- dcn GEMM: out[b,64co,px] = W[64,576] @ cols, single f16 pass ----------------
__global__ __launch_bounds__(256) void dcn_gemm_k(
    const f16* __restrict__ cols, const f16* __restrict__ wtd,
    const float* __restrict__ bias, float* __restrict__ out)
{
  const int tid = threadIdx.x;
  const int lane = tid & 63, wave = tid >> 6;
  const int b = blockIdx.x >> 8;
  const int px0 = (blockIdx.x & 255) * 64 + wave * 16;

  f32x4 acc[4];
  #pragma unroll
  for (int f = 0; f < 4; f++) acc[f] = (f32x4)0.f;

  const f16* cb = cols + (size_t)b * 18 * HW * 32
                  + ((size_t)px0 + (lane & 15)) * 32 + (lane >> 4) * 8;
  const f16* wb = wtd + (size_t)lane * 8;

  #pragma unroll 3
  for (int ch = 0; ch < 18; ch++) {
    f16x8 bh = *(const f16x8*)&cb[(size_t)ch * HW * 32];
    const f16* wc = wb + (size_t)ch * 4 * 512;
    #pragma unroll
    for (int f = 0; f < 4; f++) {
      f16x8 a = *(const f16x8*)&wc[(size_t)f * 512];
      acc[f] = __builtin_amdgcn_mfma_f32_16x16x32_f16(a, bh, acc[f], 0, 0, 0);
    }
  }

  const int pxo = px0 + (lane & 15);
  #pragma unroll
  for (int f = 0; f < 4; f++) {
    #pragma unroll
    for (int r = 0; r < 4; r++) {
      int co = f * 16 + (lane >> 4) * 4 + r;
      out[((size_t)b * 64 + co) * HW + pxo] = acc[f][r] + bias[co];
    }
  }
}

// ---------------- launch ----------------
extern "C" void kernel_launch(void* const* d_in, const int* in_sizes, int n_in,
                              void* d_out, int out_size, void* d_ws, size_t ws_size,
                              hipStream_t stream) {
  const float* x    = (const float*)d_in[0];
  const float* cond = (const float*)d_in[1];
  const float* flow = (const float*)d_in[2];
  const float* w1 = (const float*)d_in[3];
  const float* b1 = (const float*)d_in[4];
  const float* w2 = (const float*)d_in[5];
  const float* b2 = (const float*)d_in[6];
  const float* w3 = (const float*)d_in[7];
  const float* b3 = (const float*)d_in[8];
  const float* w4 = (const float*)d_in[9];
  const float* b4 = (const float*)d_in[10];
  const float* wD = (const float*)d_in[11];
  const float* bD = (const float*)d_in[12];
  float* out = (float*)d_out;
  const int B = 2;

  char* ws = (char*)d_ws;
  // region A (37,748,736 B): condp + hA + hB during convs; aliased by cols afterwards
  f16* cols  = (f16*)ws;
  f16* condp = (f16*)ws;                         // 2*16900*160*2 = 10,816,000
  f16* hA = (f16*)(ws + 10816000);               // 2*16900*64*2  =  4,326,400
  f16* hB = (f16*)(ws + 15142400);               //                  4,326,400
  char* pw = ws + 37748736;
  float* offb = (float*)pw;          pw += 37748736;
  f16*   mskb = (f16*)pw;            pw += 9437184;
  f16*   xt   = (f16*)pw;            pw += 4194304;
  f16*   wt1  = (f16*)pw;            pw += 184320;
  f16*   wt2  = (f16*)pw;            pw += 73728;
  f16*   wt3  = (f16*)pw;            pw += 73728;
  f16*   wt4  = (f16*)pw;            pw += 497664;
  f16*   wtd  = (f16*)pw;            pw += 73728;

  // halo zeroing + prep + weight transposes
  zero_edge_k<<<dim3((516 * 20 + 255) / 256, B), 256, 0, stream>>>((u16*)condp, 160);
  zero_edge_k<<<dim3((516 * 8 + 255) / 256, B), 256, 0, stream>>>((u16*)hA, 64);
  zero_edge_k<<<dim3((516 * 8 + 255) / 256, B), 256, 0, stream>>>((u16*)hB, 64);
  prep_cond_k<<<dim3(HW / 256, B), 256, 0, stream>>>(cond, condp);
  xtrans_k<<<dim3(B * 16 * HW / 256), 256, 0, stream>>>(x, xt, B);
  wtrans_mfma_k<<<dim3((9 * 5 * 4 * 64 + 255) / 256), 256, 0, stream>>>(w1, wt1, 133, 5, 4);
  wtrans_mfma_k<<<dim3((9 * 2 * 4 * 64 + 255) / 256), 256, 0, stream>>>(w2, wt2, 64, 2, 4);
  wtrans_mfma_k<<<dim3((9 * 2 * 4 * 64 + 255) / 256), 256, 0, stream>>>(w3, wt3, 64, 2, 4);
  wtrans_mfma_k<<<dim3((9 * 2 * 27 * 64 + 255) / 256), 256, 0, stream>>>(w4, wt4, 64, 2, 27);
  wtrans_dcn_mfma_k<<<dim3((18 * 4 * 64 + 255) / 256), 256, 0, stream>>>(wD, wtd);

  // convs (f16 MFMA, LDS-staged)
  conv_f16_k<160, 5, 1, 4, 0><<<dim3(8, 8, B * 4), 256, 0, stream>>>(
      condp, wt1, b1, hA, nullptr, nullptr, nullptr, 4);
  conv_f16_k<64, 2, 1, 4, 0><<<dim3(8, 8, B * 4), 256, 0, stream>>>(
      hA, wt2, b2, hB, nullptr, nullptr, nullptr, 4);
  conv_f16_k<64, 2, 1, 4, 0><<<dim3(8, 8, B * 4), 256, 0, stream>>>(
      hB, wt3, b3, hA, nullptr, nullptr, nullptr, 4);
  conv_f16_k<64, 2, 3, 27, 2><<<dim3(8, 8, B * 9), 256, 0, stream>>>(
      hA, wt4, b4, nullptr, offb, mskb, flow, 9);

  // deformable conv: sample (LDS-transposed, coalesced) -> f16 im2col -> MFMA GEMM
  dcn_sample_k<<<dim3(HW / 16, B), 256, 0, stream>>>(xt, offb, mskb, cols);
  dcn_gemm_k<<<dim3(512), 256, 0, stream>>>(cols, wtd, bD, out);
}

// Round 7
// 180.308 us; speedup vs baseline: 1.7557x; 1.1301x over previous
//
#include <hip/hip_runtime.h>
#include <math.h>

#define Hh 128
#define Ww 128
#define HW (128*128)
#define PITCH 130
#define PADPX (130*130)

typedef unsigned short u16;
typedef unsigned int uint;
typedef _Float16 f16;
typedef __attribute__((ext_vector_type(8))) _Float16 f16x8;
typedef __attribute__((ext_vector_type(4))) _Float16 f16x4;
typedef __attribute__((ext_vector_type(4))) float f32x4;

// ---------------- zero halo edges of padded NHWC f16 buffer ----------------
__global__ __launch_bounds__(256) void zero_edge_k(u16* __restrict__ buf, int cu16) {
  int per_px = cu16 >> 3;           // uint4 chunks per pixel
  int total = 516 * per_px;
  int idx = blockIdx.x * 256 + threadIdx.x;
  int b = blockIdx.y;
  if (idx >= total) return;
  int e = idx / per_px, q = idx - e * per_px;
  int y, x;
  if (e < 130)      { y = 0;   x = e; }
  else if (e < 260) { y = 129; x = e - 130; }
  else { int j = e - 260; y = 1 + (j >> 1); x = (j & 1) ? 129 : 0; }
  *(uint4*)&buf[((size_t)b * PADPX + (size_t)(y * PITCH + x)) * cu16 + q * 8] =
      make_uint4(0, 0, 0, 0);
}

// ---------------- prep: cond [B][133][HW] f32 -> padded NHWC f16 [B][PADPX][160] ----------------
__global__ __launch_bounds__(256) void prep_cond_k(const float* __restrict__ cond,
                                                   f16* __restrict__ out) {
  int p = blockIdx.x * 256 + threadIdx.x;
  int b = blockIdx.y;
  int y = p >> 7, x = p & 127;
  const float* cb = cond + (size_t)b * 133 * HW + p;
  f16* ob = out + ((size_t)b * PADPX + (size_t)((y + 1) * PITCH + x + 1)) * 160;
  for (int c = 0; c < 160; c += 8) {
    f16 buf[8];
    #pragma unroll
    for (int j = 0; j < 8; j++) {
      float v = (c + j < 133) ? cb[(size_t)(c + j) * HW] : 0.f;
      buf[j] = (f16)v;
    }
    *(uint4*)&ob[c] = *(uint4*)buf;
  }
}

// ---------------- conv weight -> f16 MFMA A-frags: frag = (t*NC + c)*NCOF + f ----------------
__global__ __launch_bounds__(256) void wtrans_mfma_k(const float* __restrict__ w,
                                                     f16* __restrict__ wt,
                                                     int CIN, int NC, int NCOF) {
  int idx = blockIdx.x * 256 + threadIdx.x;
  int total = 9 * NC * NCOF * 64;
  if (idx >= total) return;
  int lane = idx & 63;
  int frag = idx >> 6;
  int f = frag % NCOF;
  int rest = frag / NCOF;
  int c = rest % NC;
  int t = rest / NC;
  int co = f * 16 + (lane & 15);
  int ci0 = c * 32 + (lane >> 4) * 8;
  f16 buf[8];
  #pragma unroll
  for (int j = 0; j < 8; j++) {
    int ci = ci0 + j;
    buf[j] = (f16)((ci < CIN) ? w[((size_t)co * CIN + ci) * 9 + t] : 0.f);
  }
  *(uint4*)&wt[(size_t)idx * 8] = *(uint4*)buf;
}

// ---------------- dcn weight -> f16 A-frags over K=576 (ci = k*64 + dg*4 + c) ----------------
__global__ __launch_bounds__(256) void wtrans_dcn_mfma_k(const float* __restrict__ w,
                                                         f16* __restrict__ wt) {
  int idx = blockIdx.x * 256 + threadIdx.x;
  if (idx >= 18 * 4 * 64) return;
  int lane = idx & 63;
  int frag = idx >> 6;
  int f = frag & 3;
  int chunk = frag >> 2;
  int co = f * 16 + (lane & 15);
  int ci0 = chunk * 32 + (lane >> 4) * 8;
  f16 buf[8];
  #pragma unroll
  for (int j = 0; j < 8; j++) {
    int ci = ci0 + j;
    int k = ci >> 6, cig = ci & 63;
    buf[j] = (f16)w[((size_t)co * 64 + cig) * 9 + k];
  }
  *(uint4*)&wt[(size_t)idx * 8] = *(uint4*)buf;
}

// x [B][64][H][W] f32 -> xt2 [B][16][H][W][8] f16 : (4ch @ x, 4ch @ min(x+1,127))
__global__ __launch_bounds__(256) void xtrans2_k(const float* __restrict__ x,
                                                 f16* __restrict__ xt2, int B) {
  int idx = blockIdx.x * 256 + threadIdx.x;
  int total = B * 16 * HW;
  if (idx >= total) return;
  int b = idx / (16 * HW);
  int r = idx % (16 * HW);
  int dg = r / HW, p = r % HW;
  int y = p >> 7, xx = p & 127;
  int x1 = min(xx + 1, 127);
  const float* xb = x + ((size_t)b * 64 + dg * 4) * HW + (size_t)y * Ww;
  f16 o[8];
  #pragma unroll
  for (int c = 0; c < 4; c++) {
    o[c] = (f16)xb[(size_t)c * HW + xx];
    o[4 + c] = (f16)xb[(size_t)c * HW + x1];
  }
  *(uint4*)&xt2[(size_t)idx * 8] = *(uint4*)o;
}

// ---------------- conv3x3 via f16 MFMA, single pass, LDS-staged ----------------
template<int CINP, int NC, int NCF, int NCOF, int EPI>
__global__ __launch_bounds__(256, 4) void conv_f16_k(
    const f16* __restrict__ in, const f16* __restrict__ wt,
    const float* __restrict__ bias, f16* __restrict__ out,
    float* __restrict__ offb, f16* __restrict__ mskb,
    const float* __restrict__ flow, int cogroups)
{
  __shared__ u16 lds[324 * 40];
  const int tid = threadIdx.x;
  const int lane = tid & 63, wave = tid >> 6;
  const int b = blockIdx.z / cogroups, cog = blockIdx.z % cogroups;
  const int gx0 = blockIdx.x * 16, gy0 = blockIdx.y * 16;

  f32x4 acc[4][NCF];
  #pragma unroll
  for (int i = 0; i < 4; i++)
    #pragma unroll
    for (int j = 0; j < NCF; j++) acc[i][j] = (f32x4)0.f;

  const f16* inb = in + (size_t)b * PADPX * CINP;

  for (int c = 0; c < NC; c++) {
    __syncthreads();
    for (int i = tid; i < 1296; i += 256) {
      int pidx = i >> 2, q = i & 3;
      int py = pidx / 18, px = pidx - py * 18;
      size_t gp = (size_t)((gy0 + py) * PITCH + gx0 + px);
      uint4 v = *(const uint4*)&inb[gp * CINP + c * 32 + q * 8];
      *(uint4*)&lds[pidx * 40 + q * 8] = v;
    }
    __syncthreads();

    #pragma unroll
    for (int tap = 0; tap < 9; tap++) {
      const int dy = tap / 3, dx = tap % 3;
      f16x8 bfrag[4];
      #pragma unroll
      for (int pl = 0; pl < 4; pl++) {
        int pidx_r = (wave * 4 + pl + dy) * 18 + (lane & 15) + dx;
        bfrag[pl] = *(const f16x8*)&lds[pidx_r * 40 + (lane >> 4) * 8];
      }
      const f16* fA = wt + (((size_t)(tap * NC + c)) * NCOF + cog * NCF) * 512
                      + (size_t)lane * 8;
      #pragma unroll
      for (int cf = 0; cf < NCF; cf++) {
        f16x8 a = *(const f16x8*)&fA[(size_t)cf * 512];
        #pragma unroll
        for (int pl = 0; pl < 4; pl++)
          acc[pl][cf] = __builtin_amdgcn_mfma_f32_16x16x32_f16(a, bfrag[pl], acc[pl][cf], 0, 0, 0);
      }
    }
  }

  const int co_l = (lane >> 4) * 4;
  if (EPI == 0) {
    #pragma unroll
    for (int pl = 0; pl < 4; pl++) {
      size_t pp = (size_t)((gy0 + wave * 4 + pl + 1) * PITCH + gx0 + (lane & 15) + 1);
      f16* ob = out + ((size_t)b * PADPX + pp) * (NCOF * 16);
      #pragma unroll
      for (int cf = 0; cf < NCF; cf++) {
        int c0 = (cog * NCF + cf) * 16 + co_l;
        f16 buf[4];
        #pragma unroll
        for (int r = 0; r < 4; r++) {
          float v = acc[pl][cf][r] + bias[c0 + r];
          buf[r] = (f16)((v >= 0.f) ? v : 0.1f * v);
        }
        *(uint2*)&ob[c0] = *(uint2*)buf;
      }
    }
  } else {
    #pragma unroll
    for (int pl = 0; pl < 4; pl++) {
      size_t pix = (size_t)(gy0 + wave * 4 + pl) * Ww + gx0 + (lane & 15);
      float fl0 = flow[((size_t)b * 2 + 0) * HW + pix];
      float fl1 = flow[((size_t)b * 2 + 1) * HW + pix];
      #pragma unroll
      for (int cf = 0; cf < NCF; cf++) {
        int c0 = (cog * NCF + cf) * 16 + co_l;
        #pragma unroll
        for (int r = 0; r < 4; r++) {
          int cc = c0 + r;
          float v = acc[pl][cf][r] + bias[cc];
          if (cc < 288) {
            float e = __expf(2.f * v);
            float t = 1.f - 2.f * __builtin_amdgcn_rcpf(e + 1.f);
            offb[((size_t)b * 288 + cc) * HW + pix] = 10.f * t + ((cc & 1) ? fl0 : fl1);
          } else {
            mskb[((size_t)b * 144 + (cc - 288)) * HW + pix] =
                (f16)__builtin_amdgcn_rcpf(1.f + __expf(-v));
          }
        }
      }
    }
  }
}

// ---------------- fused dcn: per-tap sample 64px x 64ci into LDS, MFMA, accumulate --------
// block: 256 thr / 4 waves; 64 px, all 64 co, K=576 (9 taps x 64).
// sampler role: pxl = tid&63, dg in {dg2*4..+3}, dg2 = tid>>6
// mfma role: wave handles px (wave*16..+15), 4 co-frags
__global__ __launch_bounds__(256) void dcn_fused_k(
    const f16* __restrict__ xt2, const float* __restrict__ off,
    const f16* __restrict__ msk, const f16* __restrict__ wtd,
    const float* __restrict__ bias, float* __restrict__ out)
{
  __shared__ u16 buf[2][64][72];
  const int tid = threadIdx.x;
  const int lane = tid & 63, wave = tid >> 6;
  const int b = blockIdx.x >> 8;
  const int px0 = (blockIdx.x & 255) * 64;
  const int pxl = tid & 63;
  const int px = px0 + pxl;
  const int y = px >> 7, x0i = px & 127;
  const int dg2 = tid >> 6;

  const float* offp = off + (size_t)b * 288 * HW + px;
  const f16*   mp   = msk + (size_t)b * 144 * HW + px;
  const f16*   xpl  = xt2 + (size_t)(b * 16 + dg2 * 4) * ((size_t)HW * 8);

  f32x4 acc[4];
  #pragma unroll
  for (int f = 0; f < 4; f++) acc[f] = (f32x4)0.f;

  float dyv[2][4], dxv[2][4], mvv[2][4];
  f16x8 g0[4], g1[4];
  float w00[4], w01[4], w10[4], w11[4];
  int hsel[4];

#define OFF_LOAD(kk, sl) { \
  _Pragma("unroll") \
  for (int i = 0; i < 4; i++) { int dg = dg2 * 4 + i; \
    dyv[sl][i] = offp[(size_t)(dg * 18 + 2 * (kk)) * HW]; \
    dxv[sl][i] = offp[(size_t)(dg * 18 + 2 * (kk) + 1) * HW]; \
    mvv[sl][i] = (float)mp[(size_t)(dg * 9 + (kk)) * HW]; } }

#define GATHER(kk, sl) { \
  _Pragma("unroll") \
  for (int i = 0; i < 4; i++) { \
    float py = (float)(y - 1 + (kk) / 3) + dyv[sl][i]; \
    float pxx = (float)(x0i - 1 + (kk) % 3) + dxv[sl][i]; \
    float y0f = floorf(py), x0f = floorf(pxx); \
    float wy = py - y0f, wx = pxx - x0f; \
    int yi = (int)y0f, xi = (int)x0f; \
    bool vy0 = (yi >= 0) & (yi < Hh); \
    bool vy1 = (yi + 1 >= 0) & (yi + 1 < Hh); \
    bool vx0 = (xi >= 0) & (xi < Ww); \
    bool vx1 = (xi + 1 >= 0) & (xi + 1 < Ww); \
    int y0c = min(max(yi, 0), Hh - 1), y1c = min(max(yi + 1, 0), Hh - 1); \
    int xb = min(max(xi, 0), Ww - 1); \
    hsel[i] = min(max(xi + 1, 0), Ww - 1) - xb; \
    float mv = mvv[sl][i]; \
    w00[i] = (vy0 && vx0) ? (1.f - wy) * (1.f - wx) * mv : 0.f; \
    w01[i] = (vy0 && vx1) ? (1.f - wy) * wx * mv : 0.f; \
    w10[i] = (vy1 && vx0) ? wy * (1.f - wx) * mv : 0.f; \
    w11[i] = (vy1 && vx1) ? wy * wx * mv : 0.f; \
    const f16* xp = xpl + (size_t)i * ((size_t)HW * 8); \
    g0[i] = *(const f16x8*)&xp[(size_t)(y0c * Ww + xb) * 8]; \
    g1[i] = *(const f16x8*)&xp[(size_t)(y1c * Ww + xb) * 8]; } }

#define FIN(nb) { \
  f16 o[16]; \
  _Pragma("unroll") \
  for (int i = 0; i < 4; i++) { \
    _Pragma("unroll") \
    for (int c = 0; c < 4; c++) { \
      float a00 = (float)g0[i][c]; \
      float a01 = hsel[i] ? (float)g0[i][4 + c] : (float)g0[i][c]; \
      float a10 = (float)g1[i][c]; \
      float a11 = hsel[i] ? (float)g1[i][4 + c] : (float)g1[i][c]; \
      o[i * 4 + c] = (f16)(a00 * w00[i] + a01 * w01[i] + a10 * w10[i] + a11 * w11[i]); } } \
  *(uint4*)&buf[nb][pxl][dg2 * 16] = *(uint4*)&o[0]; \
  *(uint4*)&buf[nb][pxl][dg2 * 16 + 8] = *(uint4*)&o[8]; }

#define MFMA_TAP(kk) { \
  _Pragma("unroll") \
  for (int ch = 0; ch < 2; ch++) { \
    f16x8 bfr = *(const f16x8*)&buf[(kk) & 1][wave * 16 + (lane & 15)][(lane >> 4) * 8 + ch * 32]; \
    const f16* wc = wtd + ((size_t)(((kk) * 2 + ch) * 4) * 64 + (size_t)lane) * 8; \
    _Pragma("unroll") \
    for (int f = 0; f < 4; f++) { \
      f16x8 a = *(const f16x8*)&wc[(size_t)f * 512]; \
      acc[f] = __builtin_amdgcn_mfma_f32_16x16x32_f16(a, bfr, acc[f], 0, 0, 0); } } }

  // prologue: sample tap 0, prefetch offs tap 1
  OFF_LOAD(0, 0);
  GATHER(0, 0);
  OFF_LOAD(1, 1);
  FIN(0);
  __syncthreads();

  #pragma unroll
  for (int k = 0; k < 9; k++) {
    if (k < 8) { GATHER(k + 1, (k + 1) & 1); }  // offs already in flight
    if (k < 7) { OFF_LOAD(k + 2, k & 1); }      // prefetch next-next offs
    MFMA_TAP(k);                                 // covers gather latency
    if (k < 8) { FIN((k + 1) & 1); }            // blend + ds_write next buf
    __syncthreads();
  }

  // epilogue
  const int pxo = px0 + wave * 16 + (lane & 15);
  #pragma unroll
  for (int f = 0; f < 4; f++) {
    #pragma unroll
    for (int r = 0; r < 4; r++) {
      int co = f * 16 + (lane >> 4) * 4 + r;
      out[((size_t)b * 64 + co) * HW + pxo] = acc[f][r] + bias[co];
    }
  }
#undef OFF_LOAD
#undef GATHER
#undef FIN
#undef MFMA_TAP
}

// ---------------- launch ----------------
extern "C" void kernel_launch(void* const* d_in, const int* in_sizes, int n_in,
                              void* d_out, int out_size, void* d_ws, size_t ws_size,
                              hipStream_t stream) {
  const float* x    = (const float*)d_in[0];
  const float* cond = (const float*)d_in[1];
  const float* flow = (const float*)d_in[2];
  const float* w1 = (const float*)d_in[3];
  const float* b1 = (const float*)d_in[4];
  const float* w2 = (const float*)d_in[5];
  const float* b2 = (const float*)d_in[6];
  const float* w3 = (const float*)d_in[7];
  const float* b3 = (const float*)d_in[8];
  const float* w4 = (const float*)d_in[9];
  const float* b4 = (const float*)d_in[10];
  const float* wD = (const float*)d_in[11];
  const float* bD = (const float*)d_in[12];
  float* out = (float*)d_out;
  const int B = 2;

  char* ws = (char*)d_ws;
  f16* condp = (f16*)ws;                         // 2*16900*160*2 = 10,816,000
  f16* hA = (f16*)(ws + 10816000);               // 2*16900*64*2  =  4,326,400
  f16* hB = (f16*)(ws + 15142400);               //                  4,326,400
  char* pw = ws + 19468800;
  float* offb = (float*)pw;          pw += 37748736;
  f16*   mskb = (f16*)pw;            pw += 9437184;
  f16*   xt2  = (f16*)pw;            pw += 8388608;
  f16*   wt1  = (f16*)pw;            pw += 184320;
  f16*   wt2  = (f16*)pw;            pw += 73728;
  f16*   wt3  = (f16*)pw;            pw += 73728;
  f16*   wt4  = (f16*)pw;            pw += 497664;
  f16*   wtd  = (f16*)pw;            pw += 73728;

  // halo zeroing + prep + weight transposes
  zero_edge_k<<<dim3((516 * 20 + 255) / 256, B), 256, 0, stream>>>((u16*)condp, 160);
  zero_edge_k<<<dim3((516 * 8 + 255) / 256, B), 256, 0, stream>>>((u16*)hA, 64);
  zero_edge_k<<<dim3((516 * 8 + 255) / 256, B), 256, 0, stream>>>((u16*)hB, 64);
  prep_cond_k<<<dim3(HW / 256, B), 256, 0, stream>>>(cond, condp);
  xtrans2_k<<<dim3(B * 16 * HW / 256), 256, 0, stream>>>(x, xt2, B);
  wtrans_mfma_k<<<dim3((9 * 5 * 4 * 64 + 255) / 256), 256, 0, stream>>>(w1, wt1, 133, 5, 4);
  wtrans_mfma_k<<<dim3((9 * 2 * 4 * 64 + 255) / 256), 256, 0, stream>>>(w2, wt2, 64, 2, 4);
  wtrans_mfma_k<<<dim3((9 * 2 * 4 * 64 + 255) / 256), 256, 0, stream>>>(w3, wt3, 64, 2, 4);
  wtrans_mfma_k<<<dim3((9 * 2 * 27 * 64 + 255) / 256), 256, 0, stream>>>(w4, wt4, 64, 2, 27);
  wtrans_dcn_mfma_k<<<dim3((18 * 4 * 64 + 255) / 256), 256, 0, stream>>>(wD, wtd);

  // convs (f16 MFMA, LDS-staged)
  conv_f16_k<160, 5, 1, 4, 0><<<dim3(8, 8, B * 4), 256, 0, stream>>>(
      condp, wt1, b1, hA, nullptr, nullptr, nullptr, 4);
  conv_f16_k<64, 2, 1, 4, 0><<<dim3(8, 8, B * 4), 256, 0, stream>>>(
      hA, wt2, b2, hB, nullptr, nullptr, nullptr, 4);
  conv_f16_k<64, 2, 1, 4, 0><<<dim3(8, 8, B * 4), 256, 0, stream>>>(
      hB, wt3, b3, hA, nullptr, nullptr, nullptr, 4);
  conv_f16_k<64, 2, 3, 27, 2><<<dim3(8, 8, B * 9), 256, 0, stream>>>(
      hA, wt4, b4, nullptr, offb, mskb, flow, 9);

  // fused deformable conv: sample -> LDS -> MFMA, no cols round-trip
  dcn_fused_k<<<dim3(512), 256, 0, stream>>>(xt2, offb, mskb, wtd, bD, out);
}

// Round 8
// 149.287 us; speedup vs baseline: 2.1205x; 1.2078x over previous
//
#include <hip/hip_runtime.h>
#include <math.h>

#define Hh 128
#define Ww 128
#define HW (128*128)
#define PITCH 130
#define PADPX (130*130)

typedef unsigned short u16;
typedef unsigned int uint;
typedef _Float16 f16;
typedef __attribute__((ext_vector_type(8))) _Float16 f16x8;
typedef __attribute__((ext_vector_type(4))) _Float16 f16x4;
typedef __attribute__((ext_vector_type(4))) float f32x4;

// ---------------- zero halo edges of padded NHWC f16 buffer ----------------
__global__ __launch_bounds__(256) void zero_edge_k(u16* __restrict__ buf, int cu16) {
  int per_px = cu16 >> 3;           // uint4 chunks per pixel
  int total = 516 * per_px;
  int idx = blockIdx.x * 256 + threadIdx.x;
  int b = blockIdx.y;
  if (idx >= total) return;
  int e = idx / per_px, q = idx - e * per_px;
  int y, x;
  if (e < 130)      { y = 0;   x = e; }
  else if (e < 260) { y = 129; x = e - 130; }
  else { int j = e - 260; y = 1 + (j >> 1); x = (j & 1) ? 129 : 0; }
  *(uint4*)&buf[((size_t)b * PADPX + (size_t)(y * PITCH + x)) * cu16 + q * 8] =
      make_uint4(0, 0, 0, 0);
}

// ---------------- prep: cond [B][133][HW] f32 -> padded NHWC f16 [B][PADPX][160] ----------------
__global__ __launch_bounds__(256) void prep_cond_k(const float* __restrict__ cond,
                                                   f16* __restrict__ out) {
  int p = blockIdx.x * 256 + threadIdx.x;
  int b = blockIdx.y;
  int y = p >> 7, x = p & 127;
  const float* cb = cond + (size_t)b * 133 * HW + p;
  f16* ob = out + ((size_t)b * PADPX + (size_t)((y + 1) * PITCH + x + 1)) * 160;
  for (int c = 0; c < 160; c += 8) {
    f16 buf[8];
    #pragma unroll
    for (int j = 0; j < 8; j++) {
      float v = (c + j < 133) ? cb[(size_t)(c + j) * HW] : 0.f;
      buf[j] = (f16)v;
    }
    *(uint4*)&ob[c] = *(uint4*)buf;
  }
}

// ---------------- conv weight -> f16 MFMA A-frags: frag = (t*NC + c)*NCOF + f ----------------
__global__ __launch_bounds__(256) void wtrans_mfma_k(const float* __restrict__ w,
                                                     f16* __restrict__ wt,
                                                     int CIN, int NC, int NCOF) {
  int idx = blockIdx.x * 256 + threadIdx.x;
  int total = 9 * NC * NCOF * 64;
  if (idx >= total) return;
  int lane = idx & 63;
  int frag = idx >> 6;
  int f = frag % NCOF;
  int rest = frag / NCOF;
  int c = rest % NC;
  int t = rest / NC;
  int co = f * 16 + (lane & 15);
  int ci0 = c * 32 + (lane >> 4) * 8;
  f16 buf[8];
  #pragma unroll
  for (int j = 0; j < 8; j++) {
    int ci = ci0 + j;
    buf[j] = (f16)((ci < CIN) ? w[((size_t)co * CIN + ci) * 9 + t] : 0.f);
  }
  *(uint4*)&wt[(size_t)idx * 8] = *(uint4*)buf;
}

// ---------------- dcn weight -> f16 A-frags over K=576 (ci = k*64 + dg*4 + c) ----------------
__global__ __launch_bounds__(256) void wtrans_dcn_mfma_k(const float* __restrict__ w,
                                                         f16* __restrict__ wt) {
  int idx = blockIdx.x * 256 + threadIdx.x;
  if (idx >= 18 * 4 * 64) return;
  int lane = idx & 63;
  int frag = idx >> 6;
  int f = frag & 3;
  int chunk = frag >> 2;
  int co = f * 16 + (lane & 15);
  int ci0 = chunk * 32 + (lane >> 4) * 8;
  f16 buf[8];
  #pragma unroll
  for (int j = 0; j < 8; j++) {
    int ci = ci0 + j;
    int k = ci >> 6, cig = ci & 63;
    buf[j] = (f16)w[((size_t)co * 64 + cig) * 9 + k];
  }
  *(uint4*)&wt[(size_t)idx * 8] = *(uint4*)buf;
}

// x [B][64][H][W] f32 -> xt2 [B][16][H][W][8] f16 : (4ch @ x, 4ch @ min(x+1,127))
__global__ __launch_bounds__(256) void xtrans2_k(const float* __restrict__ x,
                                                 f16* __restrict__ xt2, int B) {
  int idx = blockIdx.x * 256 + threadIdx.x;
  int total = B * 16 * HW;
  if (idx >= total) return;
  int b = idx / (16 * HW);
  int r = idx % (16 * HW);
  int dg = r / HW, p = r % HW;
  int y = p >> 7, xx = p & 127;
  int x1 = min(xx + 1, 127);
  const float* xb = x + ((size_t)b * 64 + dg * 4) * HW + (size_t)y * Ww;
  f16 o[8];
  #pragma unroll
  for (int c = 0; c < 4; c++) {
    o[c] = (f16)xb[(size_t)c * HW + xx];
    o[4 + c] = (f16)xb[(size_t)c * HW + x1];
  }
  *(uint4*)&xt2[(size_t)idx * 8] = *(uint4*)o;
}

// ---------------- conv3x3 via f16 MFMA, 16x8 tile, LDS-staged ----------------
// Block = 256 thr / 4 waves; wave owns 2 px-rows of 16. 10x18 halo staged per 32-ci chunk.
template<int CINP, int NC, int NCF, int NCOF, int EPI>
__global__ __launch_bounds__(256) void conv_f16_k(
    const f16* __restrict__ in, const f16* __restrict__ wt,
    const float* __restrict__ bias, f16* __restrict__ out,
    float* __restrict__ offb, f16* __restrict__ mskb,
    const float* __restrict__ flow, int cogroups)
{
  __shared__ u16 lds[180 * 40];
  const int tid = threadIdx.x;
  const int lane = tid & 63, wave = tid >> 6;
  const int b = blockIdx.z / cogroups, cog = blockIdx.z % cogroups;
  const int gx0 = blockIdx.x * 16, gy0 = blockIdx.y * 8;

  f32x4 acc[2][NCF];
  #pragma unroll
  for (int i = 0; i < 2; i++)
    #pragma unroll
    for (int j = 0; j < NCF; j++) acc[i][j] = (f32x4)0.f;

  const f16* inb = in + (size_t)b * PADPX * CINP;

  for (int c = 0; c < NC; c++) {
    __syncthreads();
    // stage 10x18 halo x 32 ci: 180 px * 4 quads of 16B
    for (int i = tid; i < 720; i += 256) {
      int pidx = i >> 2, q = i & 3;
      int py = pidx / 18, px = pidx - py * 18;
      size_t gp = (size_t)((gy0 + py) * PITCH + gx0 + px);
      uint4 v = *(const uint4*)&inb[gp * CINP + c * 32 + q * 8];
      *(uint4*)&lds[pidx * 40 + q * 8] = v;
    }
    __syncthreads();

    #pragma unroll
    for (int tap = 0; tap < 9; tap++) {
      const int dy = tap / 3, dx = tap % 3;
      f16x8 bfrag[2];
      #pragma unroll
      for (int pl = 0; pl < 2; pl++) {
        int pidx_r = (wave * 2 + pl + dy) * 18 + (lane & 15) + dx;
        bfrag[pl] = *(const f16x8*)&lds[pidx_r * 40 + (lane >> 4) * 8];
      }
      const f16* fA = wt + (((size_t)(tap * NC + c)) * NCOF + cog * NCF) * 512
                      + (size_t)lane * 8;
      #pragma unroll
      for (int cf = 0; cf < NCF; cf++) {
        f16x8 a = *(const f16x8*)&fA[(size_t)cf * 512];
        #pragma unroll
        for (int pl = 0; pl < 2; pl++)
          acc[pl][cf] = __builtin_amdgcn_mfma_f32_16x16x32_f16(a, bfrag[pl], acc[pl][cf], 0, 0, 0);
      }
    }
  }

  const int co_l = (lane >> 4) * 4;
  if (EPI == 0) {
    #pragma unroll
    for (int pl = 0; pl < 2; pl++) {
      size_t pp = (size_t)((gy0 + wave * 2 + pl + 1) * PITCH + gx0 + (lane & 15) + 1);
      f16* ob = out + ((size_t)b * PADPX + pp) * (NCOF * 16);
      #pragma unroll
      for (int cf = 0; cf < NCF; cf++) {
        int c0 = (cog * NCF + cf) * 16 + co_l;
        f16 buf[4];
        #pragma unroll
        for (int r = 0; r < 4; r++) {
          float v = acc[pl][cf][r] + bias[c0 + r];
          buf[r] = (f16)((v >= 0.f) ? v : 0.1f * v);
        }
        *(uint2*)&ob[c0] = *(uint2*)buf;
      }
    }
  } else {
    #pragma unroll
    for (int pl = 0; pl < 2; pl++) {
      size_t pix = (size_t)(gy0 + wave * 2 + pl) * Ww + gx0 + (lane & 15);
      float fl0 = flow[((size_t)b * 2 + 0) * HW + pix];
      float fl1 = flow[((size_t)b * 2 + 1) * HW + pix];
      #pragma unroll
      for (int cf = 0; cf < NCF; cf++) {
        int c0 = (cog * NCF + cf) * 16 + co_l;
        #pragma unroll
        for (int r = 0; r < 4; r++) {
          int cc = c0 + r;
          float v = acc[pl][cf][r] + bias[cc];
          if (cc < 288) {
            float e = __expf(2.f * v);
            float t = 1.f - 2.f * __builtin_amdgcn_rcpf(e + 1.f);
            offb[((size_t)b * 288 + cc) * HW + pix] = 10.f * t + ((cc & 1) ? fl0 : fl1);
          } else {
            mskb[((size_t)b * 144 + (cc - 288)) * HW + pix] =
                (f16)__builtin_amdgcn_rcpf(1.f + __expf(-v));
          }
        }
      }
    }
  }
}

// ---------------- fused dcn: per-tap sample 64px x 64ci into LDS, MFMA, accumulate --------
// XCD-bijective swizzle: 512 blocks = 8 XCDs x 64; each XCD gets a contiguous 32-row band.
__global__ __launch_bounds__(256) void dcn_fused_k(
    const f16* __restrict__ xt2, const float* __restrict__ off,
    const f16* __restrict__ msk, const f16* __restrict__ wtd,
    const float* __restrict__ bias, float* __restrict__ out)
{
  __shared__ u16 buf[2][64][72];
  const int tid = threadIdx.x;
  const int lane = tid & 63, wave = tid >> 6;
  const int bid = blockIdx.x;
  const int nid = (bid & 7) * 64 + (bid >> 3);   // XCD-contiguous remap (512 = 8*64)
  const int b = nid >> 8;
  const int px0 = (nid & 255) * 64;
  const int pxl = tid & 63;
  const int px = px0 + pxl;
  const int y = px >> 7, x0i = px & 127;
  const int dg2 = tid >> 6;

  const float* offp = off + (size_t)b * 288 * HW + px;
  const f16*   mp   = msk + (size_t)b * 144 * HW + px;
  const f16*   xpl  = xt2 + (size_t)(b * 16 + dg2 * 4) * ((size_t)HW * 8);

  f32x4 acc[4];
  #pragma unroll
  for (int f = 0; f < 4; f++) acc[f] = (f32x4)0.f;

  float dyv[2][4], dxv[2][4], mvv[2][4];
  f16x8 g0[4], g1[4];
  float w00[4], w01[4], w10[4], w11[4];
  int hsel[4];

#define OFF_LOAD(kk, sl) { \
  _Pragma("unroll") \
  for (int i = 0; i < 4; i++) { int dg = dg2 * 4 + i; \
    dyv[sl][i] = offp[(size_t)(dg * 18 + 2 * (kk)) * HW]; \
    dxv[sl][i] = offp[(size_t)(dg * 18 + 2 * (kk) + 1) * HW]; \
    mvv[sl][i] = (float)mp[(size_t)(dg * 9 + (kk)) * HW]; } }

#define GATHER(kk, sl) { \
  _Pragma("unroll") \
  for (int i = 0; i < 4; i++) { \
    float py = (float)(y - 1 + (kk) / 3) + dyv[sl][i]; \
    float pxx = (float)(x0i - 1 + (kk) % 3) + dxv[sl][i]; \
    float y0f = floorf(py), x0f = floorf(pxx); \
    float wy = py - y0f, wx = pxx - x0f; \
    int yi = (int)y0f, xi = (int)x0f; \
    bool vy0 = (yi >= 0) & (yi < Hh); \
    bool vy1 = (yi + 1 >= 0) & (yi + 1 < Hh); \
    bool vx0 = (xi >= 0) & (xi < Ww); \
    bool vx1 = (xi + 1 >= 0) & (xi + 1 < Ww); \
    int y0c = min(max(yi, 0), Hh - 1), y1c = min(max(yi + 1, 0), Hh - 1); \
    int xb = min(max(xi, 0), Ww - 1); \
    hsel[i] = min(max(xi + 1, 0), Ww - 1) - xb; \
    float mv = mvv[sl][i]; \
    w00[i] = (vy0 && vx0) ? (1.f - wy) * (1.f - wx) * mv : 0.f; \
    w01[i] = (vy0 && vx1) ? (1.f - wy) * wx * mv : 0.f; \
    w10[i] = (vy1 && vx0) ? wy * (1.f - wx) * mv : 0.f; \
    w11[i] = (vy1 && vx1) ? wy * wx * mv : 0.f; \
    const f16* xp = xpl + (size_t)i * ((size_t)HW * 8); \
    g0[i] = *(const f16x8*)&xp[(size_t)(y0c * Ww + xb) * 8]; \
    g1[i] = *(const f16x8*)&xp[(size_t)(y1c * Ww + xb) * 8]; } }

#define FIN(nb) { \
  f16 o[16]; \
  _Pragma("unroll") \
  for (int i = 0; i < 4; i++) { \
    _Pragma("unroll") \
    for (int c = 0; c < 4; c++) { \
      float a00 = (float)g0[i][c]; \
      float a01 = hsel[i] ? (float)g0[i][4 + c] : (float)g0[i][c]; \
      float a10 = (float)g1[i][c]; \
      float a11 = hsel[i] ? (float)g1[i][4 + c] : (float)g1[i][c]; \
      o[i * 4 + c] = (f16)(a00 * w00[i] + a01 * w01[i] + a10 * w10[i] + a11 * w11[i]); } } \
  *(uint4*)&buf[nb][pxl][dg2 * 16] = *(uint4*)&o[0]; \
  *(uint4*)&buf[nb][pxl][dg2 * 16 + 8] = *(uint4*)&o[8]; }

#define MFMA_TAP(kk) { \
  _Pragma("unroll") \
  for (int ch = 0; ch < 2; ch++) { \
    f16x8 bfr = *(const f16x8*)&buf[(kk) & 1][wave * 16 + (lane & 15)][(lane >> 4) * 8 + ch * 32]; \
    const f16* wc = wtd + ((size_t)(((kk) * 2 + ch) * 4) * 64 + (size_t)lane) * 8; \
    _Pragma("unroll") \
    for (int f = 0; f < 4; f++) { \
      f16x8 a = *(const f16x8*)&wc[(size_t)f * 512]; \
      acc[f] = __builtin_amdgcn_mfma_f32_16x16x32_f16(a, bfr, acc[f], 0, 0, 0); } } }

  // prologue: sample tap 0, prefetch offs tap 1
  OFF_LOAD(0, 0);
  GATHER(0, 0);
  OFF_LOAD(1, 1);
  FIN(0);
  __syncthreads();

  #pragma unroll
  for (int k = 0; k < 9; k++) {
    if (k < 8) { GATHER(k + 1, (k + 1) & 1); }  // offs already in flight
    if (k < 7) { OFF_LOAD(k + 2, k & 1); }      // prefetch next-next offs
    MFMA_TAP(k);                                 // covers gather latency
    if (k < 8) { FIN((k + 1) & 1); }            // blend + ds_write next buf
    __syncthreads();
  }

  // epilogue
  const int pxo = px0 + wave * 16 + (lane & 15);
  #pragma unroll
  for (int f = 0; f < 4; f++) {
    #pragma unroll
    for (int r = 0; r < 4; r++) {
      int co = f * 16 + (lane >> 4) * 4 + r;
      out[((size_t)b * 64 + co) * HW + pxo] = acc[f][r] + bias[co];
    }
  }
#undef OFF_LOAD
#undef GATHER
#undef FIN
#undef MFMA_TAP
}

// ---------------- launch ----------------
extern "C" void kernel_launch(void* const* d_in, const int* in_sizes, int n_in,
                              void* d_out, int out_size, void* d_ws, size_t ws_size,
                              hipStream_t stream) {
  const float* x    = (const float*)d_in[0];
  const float* cond = (const float*)d_in[1];
  const float* flow = (const float*)d_in[2];
  const float* w1 = (const float*)d_in[3];
  const float* b1 = (const float*)d_in[4];
  const float* w2 = (const float*)d_in[5];
  const float* b2 = (const float*)d_in[6];
  const float* w3 = (const float*)d_in[7];
  const float* b3 = (const float*)d_in[8];
  const float* w4 = (const float*)d_in[9];
  const float* b4 = (const float*)d_in[10];
  const float* wD = (const float*)d_in[11];
  const float* bD = (const float*)d_in[12];
  float* out = (float*)d_out;
  const int B = 2;

  char* ws = (char*)d_ws;
  f16* condp = (f16*)ws;                         // 2*16900*160*2 = 10,816,000
  f16* hA = (f16*)(ws + 10816000);               // 2*16900*64*2  =  4,326,400
  f16* hB = (f16*)(ws + 15142400);               //                  4,326,400
  char* pw = ws + 19468800;
  float* offb = (float*)pw;          pw += 37748736;
  f16*   mskb = (f16*)pw;            pw += 9437184;
  f16*   xt2  = (f16*)pw;            pw += 8388608;
  f16*   wt1  = (f16*)pw;            pw += 184320;
  f16*   wt2  = (f16*)pw;            pw += 73728;
  f16*   wt3  = (f16*)pw;            pw += 73728;
  f16*   wt4  = (f16*)pw;            pw += 497664;
  f16*   wtd  = (f16*)pw;            pw += 73728;

  // halo zeroing + prep + weight transposes
  zero_edge_k<<<dim3((516 * 20 + 255) / 256, B), 256, 0, stream>>>((u16*)condp, 160);
  zero_edge_k<<<dim3((516 * 8 + 255) / 256, B), 256, 0, stream>>>((u16*)hA, 64);
  zero_edge_k<<<dim3((516 * 8 + 255) / 256, B), 256, 0, stream>>>((u16*)hB, 64);
  prep_cond_k<<<dim3(HW / 256, B), 256, 0, stream>>>(cond, condp);
  xtrans2_k<<<dim3(B * 16 * HW / 256), 256, 0, stream>>>(x, xt2, B);
  wtrans_mfma_k<<<dim3((9 * 5 * 4 * 64 + 255) / 256), 256, 0, stream>>>(w1, wt1, 133, 5, 4);
  wtrans_mfma_k<<<dim3((9 * 2 * 4 * 64 + 255) / 256), 256, 0, stream>>>(w2, wt2, 64, 2, 4);
  wtrans_mfma_k<<<dim3((9 * 2 * 4 * 64 + 255) / 256), 256, 0, stream>>>(w3, wt3, 64, 2, 4);
  wtrans_mfma_k<<<dim3((9 * 2 * 27 * 64 + 255) / 256), 256, 0, stream>>>(w4, wt4, 64, 2, 27);
  wtrans_dcn_mfma_k<<<dim3((18 * 4 * 64 + 255) / 256), 256, 0, stream>>>(wD, wtd);

  // convs (f16 MFMA, 16x8 tiles for occupancy)
  conv_f16_k<160, 5, 1, 4, 0><<<dim3(8, 16, B * 4), 256, 0, stream>>>(
      condp, wt1, b1, hA, nullptr, nullptr, nullptr, 4);
  conv_f16_k<64, 2, 1, 4, 0><<<dim3(8, 16, B * 4), 256, 0, stream>>>(
      hA, wt2, b2, hB, nullptr, nullptr, nullptr, 4);
  conv_f16_k<64, 2, 1, 4, 0><<<dim3(8, 16, B * 4), 256, 0, stream>>>(
      hB, wt3, b3, hA, nullptr, nullptr, nullptr, 4);
  conv_f16_k<64, 2, 3, 27, 2><<<dim3(8, 16, B * 9), 256, 0, stream>>>(
      hA, wt4, b4, nullptr, offb, mskb, flow, 9);

  // fused deformable conv (XCD-swizzled): sample -> LDS -> MFMA
  dcn_fused_k<<<dim3(512), 256, 0, stream>>>(xt2, offb, mskb, wtd, bD, out);
}